// Round 7
// baseline (335.585 us; speedup 1.0000x reference)
//
#include <hip/hip_runtime.h>

typedef unsigned short u16;
typedef unsigned int u32;
typedef __attribute__((ext_vector_type(8))) short bf16x8;
typedef __attribute__((ext_vector_type(4))) float f32x4;
#define MFMA __builtin_amdgcn_mfma_f32_16x16x32_bf16

#define TT 256
#define DD 512
#define HH 8
#define DHH 64
#define NC 2560   // 5*H*DH

__device__ __forceinline__ u16 f2bf(float f) {
    u32 x; __builtin_memcpy(&x, &f, 4);
    u32 r = (x + 0x7FFFu + ((x >> 16) & 1u)) >> 16;
    return (u16)r;
}
__device__ __forceinline__ void unpack2(u32 u, float& lo, float& hi) {
    u32 l = u << 16, h = u & 0xFFFF0000u;
    __builtin_memcpy(&lo, &l, 4); __builtin_memcpy(&hi, &h, 4);
}
__device__ __forceinline__ float sum8v(bf16x8 v) {
    uint4 u; __builtin_memcpy(&u, &v, 16);
    float f[8];
    unpack2(u.x, f[0], f[1]); unpack2(u.y, f[2], f[3]);
    unpack2(u.z, f[4], f[5]); unpack2(u.w, f[6], f[7]);
    return ((f[0]+f[1])+(f[2]+f[3]))+((f[4]+f[5])+(f[6]+f[7]));
}

// ---------------- K0: prep — Wt = bf16(W_kkqvv)^T, Wot = bf16(W_out)^T, xb = bf16(x)
__global__ __launch_bounds__(256) void prep_kernel(
    const float* __restrict__ W1, const float* __restrict__ Wo,
    const float* __restrict__ x,
    u16* __restrict__ Wt, u16* __restrict__ Wot, u16* __restrict__ xb) {
    __shared__ float S[64 * 65];
    const int bid = blockIdx.x, tid = threadIdx.x;
    if (bid < 384) {
        int tc, tr, Cw;
        const float* src; u16* dst;
        if (bid < 320) { tc = bid % 40; tr = bid / 40; src = W1; dst = Wt;  Cw = 2560; }
        else { int b2 = bid - 320; tc = b2 % 8; tr = b2 / 8; src = Wo; dst = Wot; Cw = 512; }
        {
            int X = tid >> 2, c0 = (tid & 3) * 16;
            const float4* s4 = (const float4*)(src + (size_t)(tr * 64 + X) * Cw + tc * 64 + c0);
            float4 v0 = s4[0], v1 = s4[1], v2 = s4[2], v3 = s4[3];
            float* d = &S[X * 65 + c0];
            d[0]=v0.x; d[1]=v0.y; d[2]=v0.z; d[3]=v0.w;
            d[4]=v1.x; d[5]=v1.y; d[6]=v1.z; d[7]=v1.w;
            d[8]=v2.x; d[9]=v2.y; d[10]=v2.z; d[11]=v2.w;
            d[12]=v3.x; d[13]=v3.y; d[14]=v3.z; d[15]=v3.w;
        }
        __syncthreads();
        {
            int Y = tid >> 2, x0 = (tid & 3) * 16;
            __attribute__((aligned(16))) u16 tmp[16];
#pragma unroll
            for (int xx = 0; xx < 16; ++xx) tmp[xx] = f2bf(S[(x0 + xx) * 65 + Y]);
            u16* o = dst + (size_t)(tc * 64 + Y) * 512 + tr * 64 + x0;
            *(uint4*)o = *(uint4*)tmp;
            *(uint4*)(o + 8) = *(uint4*)(tmp + 8);
        }
    } else {
        int b3 = bid - 384;            // 8 blocks cast x -> xb
        size_t base = (size_t)(b3 * 256 + tid) * 64;
        const float4* s = (const float4*)(x + base);
#pragma unroll
        for (int i = 0; i < 8; ++i) {
            float4 lo = s[2 * i], hi = s[2 * i + 1];
            __attribute__((aligned(16))) u16 t8[8];
            t8[0]=f2bf(lo.x); t8[1]=f2bf(lo.y); t8[2]=f2bf(lo.z); t8[3]=f2bf(lo.w);
            t8[4]=f2bf(hi.x); t8[5]=f2bf(hi.y); t8[6]=f2bf(hi.z); t8[7]=f2bf(hi.w);
            ((uint4*)(xb + base))[i] = *(uint4*)t8;
        }
    }
}

// ---------------- K1: proj MFMA: proj = xb @ Wt^T + b -> fiveb (v=3 -> v1T transposed)
__global__ __launch_bounds__(256) void proj_mfma(
    const u16* __restrict__ xb, const u16* __restrict__ Wt,
    const float* __restrict__ bias, u16* __restrict__ fiveb, u16* __restrict__ v1T) {
    const int tid = threadIdx.x, w = tid >> 6, lane = tid & 63;
    const int quad = lane >> 4, l15 = lane & 15;
    const int m0 = blockIdx.x * 64 + w * 16;
    const int c0 = blockIdx.y * 64;
    f32x4 acc[4];
#pragma unroll
    for (int nt = 0; nt < 4; ++nt) acc[nt] = (f32x4){0.f, 0.f, 0.f, 0.f};
    for (int kc = 0; kc < 16; ++kc) {
        bf16x8 a = *(const bf16x8*)&xb[(size_t)(m0 + l15) * 512 + kc * 32 + quad * 8];
#pragma unroll
        for (int nt = 0; nt < 4; ++nt) {
            bf16x8 b = *(const bf16x8*)&Wt[(size_t)(c0 + nt * 16 + l15) * 512 + kc * 32 + quad * 8];
            acc[nt] = MFMA(a, b, acc[nt], 0, 0, 0);
        }
    }
#pragma unroll
    for (int nt = 0; nt < 4; ++nt) {
        const int col = c0 + nt * 16 + l15;
        const float b = bias[col];
        const int v = col >> 9, h = (col >> 6) & 7, e = col & 63;
#pragma unroll
        for (int r = 0; r < 4; ++r) {
            const int t = m0 + quad * 4 + r;
            u16 val = f2bf(acc[nt][r] + b);
            if (v == 3) v1T[(h * 64 + e) * 256 + t] = val;
            else        fiveb[((v * 8 + h) * 256 + t) * 64 + e] = val;
        }
    }
}

// ---------------- K2: transpose weights to K-contiguous bf16
__global__ __launch_bounds__(256) void transpose_w(
    const float* __restrict__ WK, const float* __restrict__ WV,
    u16* __restrict__ WKt, u16* __restrict__ WVt) {
    __shared__ float S[64 * 65];
    const int outer = blockIdx.x, n = blockIdx.y, which = blockIdx.z;
    const float* in = (which ? WV : WK) + ((size_t)(n * 64 + outer)) * 4096;
    u16* outbase = (which ? WVt : WKt) + (size_t)n * 262144;
    const int tid = threadIdx.x;
    {
        int X = tid >> 2, c0 = (tid & 3) * 16;
        const float4* s = (const float4*)(in + X * 64 + c0);
        float4 v0 = s[0], v1 = s[1], v2 = s[2], v3 = s[3];
        float* d = &S[X * 65 + c0];
        d[0]=v0.x; d[1]=v0.y; d[2]=v0.z; d[3]=v0.w;
        d[4]=v1.x; d[5]=v1.y; d[6]=v1.z; d[7]=v1.w;
        d[8]=v2.x; d[9]=v2.y; d[10]=v2.z; d[11]=v2.w;
        d[12]=v3.x; d[13]=v3.y; d[14]=v3.z; d[15]=v3.w;
    }
    __syncthreads();
    {
        int Y = tid >> 2, x0 = (tid & 3) * 16;
        __attribute__((aligned(16))) u16 tmp[16];
#pragma unroll
        for (int xx = 0; xx < 16; ++xx) tmp[xx] = f2bf(S[(x0 + xx) * 65 + Y]);
        size_t strideY = which ? 4096 : 64;
        size_t strideO = which ? 64 : 4096;
        u16* d = outbase + (size_t)Y * strideY + (size_t)outer * strideO + x0;
        *(uint4*)d = *(uint4*)tmp;
        *(uint4*)(d + 8) = *(uint4*)(tmp + 8);
    }
}

// ---------------- K3: M_all[n][t][f] = sum_j k2[t,j]*WKt[n][f][j]  (U analog)
__global__ __launch_bounds__(256, 1) void mu_gemm(
    const u16* __restrict__ fiveb, const u16* __restrict__ WKt,
    const u16* __restrict__ WVt, u16* __restrict__ M_all, u16* __restrict__ U_all) {
    __shared__ u16 Cst[256 * 64];
    const int f0 = blockIdx.x * 64, n = blockIdx.y, which = blockIdx.z;
    const u16* vec = fiveb + ((which ? 4 : 1) * HH + n) * TT * DHH;
    const u16* W = (which ? WVt : WKt) + (size_t)n * 262144;
    u16* out = (which ? U_all : M_all) + (size_t)n * 1048576;
    const int tid = threadIdx.x, w = tid >> 6, lane = tid & 63;
    const int quad = lane >> 4, l15 = lane & 15;

    bf16x8 bf[4][2];
#pragma unroll
    for (int nt = 0; nt < 4; ++nt) {
        bf[nt][0] = *(const bf16x8*)&W[(size_t)(f0 + nt * 16 + l15) * 64 + quad * 8];
        bf[nt][1] = *(const bf16x8*)&W[(size_t)(f0 + nt * 16 + l15) * 64 + 32 + quad * 8];
    }
    f32x4 acc[4][4];
#pragma unroll
    for (int mt = 0; mt < 4; ++mt) {
        int trow = w * 64 + mt * 16 + l15;
        bf16x8 a0 = *(const bf16x8*)&vec[trow * 64 + quad * 8];
        bf16x8 a1 = *(const bf16x8*)&vec[trow * 64 + 32 + quad * 8];
#pragma unroll
        for (int nt = 0; nt < 4; ++nt) {
            f32x4 c = {0.f, 0.f, 0.f, 0.f};
            c = MFMA(a0, bf[nt][0], c, 0, 0, 0);
            c = MFMA(a1, bf[nt][1], c, 0, 0, 0);
            acc[mt][nt] = c;
        }
    }
#pragma unroll
    for (int mt = 0; mt < 4; ++mt)
#pragma unroll
        for (int nt = 0; nt < 4; ++nt)
#pragma unroll
            for (int r = 0; r < 4; ++r)
                Cst[(w * 64 + mt * 16 + quad * 4 + r) * 64 + nt * 16 + l15] = f2bf(acc[mt][nt][r]);
    __syncthreads();
    const uint4* src = (const uint4*)&Cst[tid * 64];
    uint4* dst = (uint4*)(out + (size_t)tid * 4096 + f0);
#pragma unroll
    for (int i = 0; i < 8; ++i) dst[i] = src[i];
}

// ---------------- K4: fused trilinear attention — balanced fine grid, slotted atomics
// grid (528, 8): per head: b<16: qt0 (4 t's); b<80: qt1 (2 t's); b<272: qt2 (1 t); else qt3 (1 t).
__global__ __launch_bounds__(256, 6) void main_kernel(
    const u16* __restrict__ fiveb, const u16* __restrict__ v1T,
    const u16* __restrict__ M_all, const u16* __restrict__ U_all,
    float* __restrict__ Zpart, float* __restrict__ Lpart) {
    __shared__ u16 QMb[64 * 72];
    __shared__ u16 Pb[64 * 72];
    const int tid = threadIdx.x;
    const int n = blockIdx.y;
    const int b = blockIdx.x;
    int qt, t0, cnt;
    if (b < 16)       { qt = 0; t0 = b * 4;        cnt = 4; }
    else if (b < 80)  { qt = 1; t0 = (b - 16) * 2; cnt = 2; }
    else if (b < 272) { qt = 2; t0 = b - 80;       cnt = 1; }
    else              { qt = 3; t0 = b - 272;      cnt = 1; }
    const int q0 = qt * 64, nP = qt + 1;
    const int slot = t0 & 15;

    const u16* k1g = fiveb + (0 * 8 + n) * 256 * 64;
    const u16* qg  = fiveb + (2 * 8 + n) * 256 * 64;
    const u16* v1g = v1T + n * 64 * 256;
    const u16* Mg = M_all + (size_t)(n * 256) * 4096;
    const u16* Ug = U_all + (size_t)(n * 256) * 4096;

    const int w = tid >> 6, lane = tid & 63, quad = lane >> 4, l15 = lane & 15;
    const int r0 = w * 16;

    // q A-fragments: wave-local, loop-invariant -> registers
    const bf16x8 qa0 = *(const bf16x8*)&qg[(q0 + r0 + l15) * 64 + quad * 8];
    const bf16x8 qa1 = *(const bf16x8*)&qg[(q0 + r0 + l15) * 64 + 32 + quad * 8];

    f32x4 Zc[4];
#pragma unroll
    for (int nt = 0; nt < 4; ++nt) Zc[nt] = (f32x4){0.f, 0.f, 0.f, 0.f};
    float lsum = 0.f;

    for (int tt = 0; tt < cnt; ++tt) {
        const int t = t0 + tt;
        const u16* Mt = Mg + (size_t)t * 4096;
        const u16* Ut = Ug + (size_t)t * 4096;

        // QM = q . M_t^T (B streamed from global), roundtrip to A-layout
#pragma unroll
        for (int nt = 0; nt < 4; ++nt) {
            bf16x8 b0 = *(const bf16x8*)&Mt[(nt * 16 + l15) * 64 + quad * 8];
            bf16x8 b1 = *(const bf16x8*)&Mt[(nt * 16 + l15) * 64 + 32 + quad * 8];
            f32x4 c = {0.f, 0.f, 0.f, 0.f};
            c = MFMA(qa0, b0, c, 0, 0, 0);
            c = MFMA(qa1, b1, c, 0, 0, 0);
#pragma unroll
            for (int r = 0; r < 4; ++r)
                QMb[(r0 + quad * 4 + r) * 72 + nt * 16 + l15] = f2bf(c[r]);
        }
        const bf16x8 qma0 = *(const bf16x8*)&QMb[(r0 + l15) * 72 + quad * 8];
        const bf16x8 qma1 = *(const bf16x8*)&QMb[(r0 + l15) * 72 + 32 + quad * 8];

        f32x4 Gc[4];
#pragma unroll
        for (int nt = 0; nt < 4; ++nt) Gc[nt] = (f32x4){0.f, 0.f, 0.f, 0.f};

        for (int pt = 0; pt < nP; ++pt) {
            // S = QM . k1^T ; mask+exp -> Pb
#pragma unroll
            for (int nt = 0; nt < 4; ++nt) {
                bf16x8 b0 = *(const bf16x8*)&k1g[(pt * 64 + nt * 16 + l15) * 64 + quad * 8];
                bf16x8 b1 = *(const bf16x8*)&k1g[(pt * 64 + nt * 16 + l15) * 64 + 32 + quad * 8];
                f32x4 s = {0.f, 0.f, 0.f, 0.f};
                s = MFMA(qma0, b0, s, 0, 0, 0);
                s = MFMA(qma1, b1, s, 0, 0, 0);
                const int p = pt * 64 + nt * 16 + l15;
#pragma unroll
                for (int r = 0; r < 4; ++r) {
                    const int q = q0 + r0 + quad * 4 + r;
                    float wv = (p <= q && t <= q) ? __expf(s[r] * 0.015625f) : 0.f;
                    Pb[(r0 + quad * 4 + r) * 72 + nt * 16 + l15] = f2bf(wv);
                }
            }
            // P A-fragments (also provide the L row partial sums)
            bf16x8 pa0 = *(const bf16x8*)&Pb[(r0 + l15) * 72 + quad * 8];
            bf16x8 pa1 = *(const bf16x8*)&Pb[(r0 + l15) * 72 + 32 + quad * 8];
            lsum += sum8v(pa0) + sum8v(pa1);
            // G += P . v1tile
#pragma unroll
            for (int nt = 0; nt < 4; ++nt) {
                bf16x8 b0 = *(const bf16x8*)&v1g[(nt * 16 + l15) * 256 + pt * 64 + quad * 8];
                bf16x8 b1 = *(const bf16x8*)&v1g[(nt * 16 + l15) * 256 + pt * 64 + 32 + quad * 8];
                Gc[nt] = MFMA(pa0, b0, Gc[nt], 0, 0, 0);
                Gc[nt] = MFMA(pa1, b1, Gc[nt], 0, 0, 0);
            }
        }
        // Z += G . U_t  (G roundtrip via Pb, wave-local)
#pragma unroll
        for (int nt = 0; nt < 4; ++nt)
#pragma unroll
            for (int r = 0; r < 4; ++r)
                Pb[(r0 + quad * 4 + r) * 72 + nt * 16 + l15] = f2bf(Gc[nt][r]);
        bf16x8 ga0 = *(const bf16x8*)&Pb[(r0 + l15) * 72 + quad * 8];
        bf16x8 ga1 = *(const bf16x8*)&Pb[(r0 + l15) * 72 + 32 + quad * 8];
#pragma unroll
        for (int nt = 0; nt < 4; ++nt) {
            bf16x8 b0 = *(const bf16x8*)&Ut[(nt * 16 + l15) * 64 + quad * 8];
            bf16x8 b1 = *(const bf16x8*)&Ut[(nt * 16 + l15) * 64 + 32 + quad * 8];
            Zc[nt] = MFMA(ga0, b0, Zc[nt], 0, 0, 0);
            Zc[nt] = MFMA(ga1, b1, Zc[nt], 0, 0, 0);
        }
    }

    // flush into slotted partials
    float* zbase = Zpart + ((size_t)((n * 4 + qt) * 16 + slot)) * 4096;
#pragma unroll
    for (int nt = 0; nt < 4; ++nt)
#pragma unroll
        for (int r = 0; r < 4; ++r)
            atomicAdd(zbase + (r0 + quad * 4 + r) * 64 + nt * 16 + l15, Zc[nt][r]);
    lsum += __shfl_xor(lsum, 16);
    lsum += __shfl_xor(lsum, 32);
    if (quad == 0)
        atomicAdd(Lpart + ((n * 4 + qt) * 16 + slot) * 64 + r0 + l15, lsum);
}

// ---------------- K5: zn[t][h*64+e] = bf16( sum_s Zpart / sum_s Lpart )
__global__ __launch_bounds__(256) void zn_kernel(
    const float* __restrict__ Zpart, const float* __restrict__ Lpart, u16* __restrict__ zn) {
    const int flat = (blockIdx.x * 256 + threadIdx.x) * 4;
    const int t = flat >> 9, he = flat & 511, h = he >> 6, e = he & 63;
    const int qt = t >> 6, qq = t & 63;
    float4 sz = {0.f, 0.f, 0.f, 0.f};
    float sl = 0.f;
    const int gbase = (h * 4 + qt) * 16;
#pragma unroll
    for (int s = 0; s < 16; ++s) {
        const float4 v = *(const float4*)(Zpart + ((size_t)(gbase + s) * 64 + qq) * 64 + e);
        sz.x += v.x; sz.y += v.y; sz.z += v.z; sz.w += v.w;
        sl += Lpart[(gbase + s) * 64 + qq];
    }
    const float inv = 1.f / sl;
    __attribute__((aligned(8))) u16 t4[4];
    t4[0] = f2bf(sz.x * inv); t4[1] = f2bf(sz.y * inv);
    t4[2] = f2bf(sz.z * inv); t4[3] = f2bf(sz.w * inv);
    *(uint2*)(zn + flat) = *(uint2*)t4;
}

// ---------------- K6: out = zn @ Wot^T + b_out (fp32 out), MFMA
__global__ __launch_bounds__(256) void out_mfma(
    const u16* __restrict__ zn, const u16* __restrict__ Wot,
    const float* __restrict__ b_out, float* __restrict__ out) {
    const int tid = threadIdx.x, w = tid >> 6, lane = tid & 63;
    const int quad = lane >> 4, l15 = lane & 15;
    const int m0 = blockIdx.x * 64 + w * 16;
    const int c0 = blockIdx.y * 64;
    f32x4 acc[4];
#pragma unroll
    for (int nt = 0; nt < 4; ++nt) acc[nt] = (f32x4){0.f, 0.f, 0.f, 0.f};
    for (int kc = 0; kc < 16; ++kc) {
        bf16x8 a = *(const bf16x8*)&zn[(size_t)(m0 + l15) * 512 + kc * 32 + quad * 8];
#pragma unroll
        for (int nt = 0; nt < 4; ++nt) {
            bf16x8 b = *(const bf16x8*)&Wot[(size_t)(c0 + nt * 16 + l15) * 512 + kc * 32 + quad * 8];
            acc[nt] = MFMA(a, b, acc[nt], 0, 0, 0);
        }
    }
#pragma unroll
    for (int nt = 0; nt < 4; ++nt) {
        const int col = c0 + nt * 16 + l15;
        const float b = b_out[col];
#pragma unroll
        for (int r = 0; r < 4; ++r)
            out[(size_t)(m0 + quad * 4 + r) * 512 + col] = acc[nt][r] + b;
    }
}

extern "C" void kernel_launch(void* const* d_in, const int* in_sizes, int n_in,
                              void* d_out, int out_size, void* d_ws, size_t ws_size,
                              hipStream_t stream) {
    const float* x       = (const float*)d_in[0];
    const float* W_kkqvv = (const float*)d_in[1];
    const float* b_kkqvv = (const float*)d_in[2];
    const float* W_Kq    = (const float*)d_in[3];
    const float* W_Vq    = (const float*)d_in[4];
    const float* W_out   = (const float*)d_in[5];
    const float* b_out   = (const float*)d_in[6];

    char* base = (char*)d_ws;
    u16*   fiveb = (u16*)base;                      // 1,310,720 B
    u16*   WKt   = (u16*)(base + 1843200);          // 4 MB
    u16*   WVt   = (u16*)(base + 6037504);          // 4 MB
    u16*   M_all = (u16*)(base + 10231808);         // 16 MB
    u16*   U_all = (u16*)(base + 27009024);         // 16 MB
    // aliases:
    float* Zpart = (float*)(base + 1843200);        // 8 MB over WKt+WVt (dead after mu_gemm)
    u16*   Wt    = (u16*)(base + 10231808);         // dead after proj (over M_all)
    u16*   xb    = (u16*)(base + 12853248);
    u16*   Wot   = (u16*)(base + 43786240);         // 524,288 B
    u16*   v1T   = (u16*)(base + 44310528);         // 262,144 B
    u16*   zn    = (u16*)(base + 44572672);         // 262,144 B
    float* Lpart = (float*)(base + 44834816);       // 131,072 B (end ~44.97 MB)

    prep_kernel<<<392, 256, 0, stream>>>(W_kkqvv, W_out, x, Wt, Wot, xb);
    proj_mfma<<<dim3(4, 40), 256, 0, stream>>>(xb, Wt, b_kkqvv, fiveb, v1T);
    transpose_w<<<dim3(64, 8, 2), 256, 0, stream>>>(W_Kq, W_Vq, WKt, WVt);
    mu_gemm<<<dim3(64, 8, 2), 256, 0, stream>>>(fiveb, WKt, WVt, M_all, U_all);
    hipMemsetAsync(Zpart, 0, 8388608, stream);
    hipMemsetAsync(Lpart, 0, 131072, stream);
    main_kernel<<<dim3(528, 8), 256, 0, stream>>>(fiveb, v1T, M_all, U_all, Zpart, Lpart);
    zn_kernel<<<128, 256, 0, stream>>>(Zpart, Lpart, zn);
    out_mfma<<<dim3(4, 8), 256, 0, stream>>>(zn, Wot, b_out, (float*)d_out);
}

// Round 8
// 321.795 us; speedup vs baseline: 1.0429x; 1.0429x over previous
//
#include <hip/hip_runtime.h>

typedef unsigned short u16;
typedef unsigned int u32;
typedef __attribute__((ext_vector_type(8))) short bf16x8;
typedef __attribute__((ext_vector_type(4))) float f32x4;
#define MFMA __builtin_amdgcn_mfma_f32_16x16x32_bf16

#define TT 256
#define DD 512
#define HH 8
#define DHH 64
#define NC 2560   // 5*H*DH

__device__ __forceinline__ u16 f2bf(float f) {
    u32 x; __builtin_memcpy(&x, &f, 4);
    u32 r = (x + 0x7FFFu + ((x >> 16) & 1u)) >> 16;
    return (u16)r;
}
__device__ __forceinline__ void unpack2(u32 u, float& lo, float& hi) {
    u32 l = u << 16, h = u & 0xFFFF0000u;
    __builtin_memcpy(&lo, &l, 4); __builtin_memcpy(&hi, &h, 4);
}
__device__ __forceinline__ float sum8v(bf16x8 v) {
    uint4 u; __builtin_memcpy(&u, &v, 16);
    float f[8];
    unpack2(u.x, f[0], f[1]); unpack2(u.y, f[2], f[3]);
    unpack2(u.z, f[4], f[5]); unpack2(u.w, f[6], f[7]);
    return ((f[0]+f[1])+(f[2]+f[3]))+((f[4]+f[5])+(f[6]+f[7]));
}

// ---------------- K0: prep — Wt = bf16(W_kkqvv)^T, Wot = bf16(W_out)^T, xb = bf16(x)
__global__ __launch_bounds__(256) void prep_kernel(
    const float* __restrict__ W1, const float* __restrict__ Wo,
    const float* __restrict__ x,
    u16* __restrict__ Wt, u16* __restrict__ Wot, u16* __restrict__ xb) {
    __shared__ float S[64 * 65];
    const int bid = blockIdx.x, tid = threadIdx.x;
    if (bid < 384) {
        int tc, tr, Cw;
        const float* src; u16* dst;
        if (bid < 320) { tc = bid % 40; tr = bid / 40; src = W1; dst = Wt;  Cw = 2560; }
        else { int b2 = bid - 320; tc = b2 % 8; tr = b2 / 8; src = Wo; dst = Wot; Cw = 512; }
        {
            int X = tid >> 2, c0 = (tid & 3) * 16;
            const float4* s4 = (const float4*)(src + (size_t)(tr * 64 + X) * Cw + tc * 64 + c0);
            float4 v0 = s4[0], v1 = s4[1], v2 = s4[2], v3 = s4[3];
            float* d = &S[X * 65 + c0];
            d[0]=v0.x; d[1]=v0.y; d[2]=v0.z; d[3]=v0.w;
            d[4]=v1.x; d[5]=v1.y; d[6]=v1.z; d[7]=v1.w;
            d[8]=v2.x; d[9]=v2.y; d[10]=v2.z; d[11]=v2.w;
            d[12]=v3.x; d[13]=v3.y; d[14]=v3.z; d[15]=v3.w;
        }
        __syncthreads();
        {
            int Y = tid >> 2, x0 = (tid & 3) * 16;
            __attribute__((aligned(16))) u16 tmp[16];
#pragma unroll
            for (int xx = 0; xx < 16; ++xx) tmp[xx] = f2bf(S[(x0 + xx) * 65 + Y]);
            u16* o = dst + (size_t)(tc * 64 + Y) * 512 + tr * 64 + x0;
            *(uint4*)o = *(uint4*)tmp;
            *(uint4*)(o + 8) = *(uint4*)(tmp + 8);
        }
    } else {
        int b3 = bid - 384;            // 8 blocks cast x -> xb
        size_t base = (size_t)(b3 * 256 + tid) * 64;
        const float4* s = (const float4*)(x + base);
#pragma unroll
        for (int i = 0; i < 8; ++i) {
            float4 lo = s[2 * i], hi = s[2 * i + 1];
            __attribute__((aligned(16))) u16 t8[8];
            t8[0]=f2bf(lo.x); t8[1]=f2bf(lo.y); t8[2]=f2bf(lo.z); t8[3]=f2bf(lo.w);
            t8[4]=f2bf(hi.x); t8[5]=f2bf(hi.y); t8[6]=f2bf(hi.z); t8[7]=f2bf(hi.w);
            ((uint4*)(xb + base))[i] = *(uint4*)t8;
        }
    }
}

// ---------------- K1: proj MFMA: proj = xb @ Wt^T + b -> fiveb (v=3 -> v1T transposed)
__global__ __launch_bounds__(256) void proj_mfma(
    const u16* __restrict__ xb, const u16* __restrict__ Wt,
    const float* __restrict__ bias, u16* __restrict__ fiveb, u16* __restrict__ v1T) {
    const int tid = threadIdx.x, w = tid >> 6, lane = tid & 63;
    const int quad = lane >> 4, l15 = lane & 15;
    const int m0 = blockIdx.x * 64 + w * 16;
    const int c0 = blockIdx.y * 64;
    f32x4 acc[4];
#pragma unroll
    for (int nt = 0; nt < 4; ++nt) acc[nt] = (f32x4){0.f, 0.f, 0.f, 0.f};
    for (int kc = 0; kc < 16; ++kc) {
        bf16x8 a = *(const bf16x8*)&xb[(size_t)(m0 + l15) * 512 + kc * 32 + quad * 8];
#pragma unroll
        for (int nt = 0; nt < 4; ++nt) {
            bf16x8 b = *(const bf16x8*)&Wt[(size_t)(c0 + nt * 16 + l15) * 512 + kc * 32 + quad * 8];
            acc[nt] = MFMA(a, b, acc[nt], 0, 0, 0);
        }
    }
#pragma unroll
    for (int nt = 0; nt < 4; ++nt) {
        const int col = c0 + nt * 16 + l15;
        const float b = bias[col];
        const int v = col >> 9, h = (col >> 6) & 7, e = col & 63;
#pragma unroll
        for (int r = 0; r < 4; ++r) {
            const int t = m0 + quad * 4 + r;
            u16 val = f2bf(acc[nt][r] + b);
            if (v == 3) v1T[(h * 64 + e) * 256 + t] = val;
            else        fiveb[((v * 8 + h) * 256 + t) * 64 + e] = val;
        }
    }
}

// ---------------- K2: transpose weights to K-contiguous bf16
__global__ __launch_bounds__(256) void transpose_w(
    const float* __restrict__ WK, const float* __restrict__ WV,
    u16* __restrict__ WKt, u16* __restrict__ WVt) {
    __shared__ float S[64 * 65];
    const int outer = blockIdx.x, n = blockIdx.y, which = blockIdx.z;
    const float* in = (which ? WV : WK) + ((size_t)(n * 64 + outer)) * 4096;
    u16* outbase = (which ? WVt : WKt) + (size_t)n * 262144;
    const int tid = threadIdx.x;
    {
        int X = tid >> 2, c0 = (tid & 3) * 16;
        const float4* s = (const float4*)(in + X * 64 + c0);
        float4 v0 = s[0], v1 = s[1], v2 = s[2], v3 = s[3];
        float* d = &S[X * 65 + c0];
        d[0]=v0.x; d[1]=v0.y; d[2]=v0.z; d[3]=v0.w;
        d[4]=v1.x; d[5]=v1.y; d[6]=v1.z; d[7]=v1.w;
        d[8]=v2.x; d[9]=v2.y; d[10]=v2.z; d[11]=v2.w;
        d[12]=v3.x; d[13]=v3.y; d[14]=v3.z; d[15]=v3.w;
    }
    __syncthreads();
    {
        int Y = tid >> 2, x0 = (tid & 3) * 16;
        __attribute__((aligned(16))) u16 tmp[16];
#pragma unroll
        for (int xx = 0; xx < 16; ++xx) tmp[xx] = f2bf(S[(x0 + xx) * 65 + Y]);
        size_t strideY = which ? 4096 : 64;
        size_t strideO = which ? 64 : 4096;
        u16* d = outbase + (size_t)Y * strideY + (size_t)outer * strideO + x0;
        *(uint4*)d = *(uint4*)tmp;
        *(uint4*)(d + 8) = *(uint4*)(tmp + 8);
    }
}

// ---------------- K3: M_all[n][t][f] = sum_j k2[t,j]*WKt[n][f][j]  (U analog)
__global__ __launch_bounds__(256, 1) void mu_gemm(
    const u16* __restrict__ fiveb, const u16* __restrict__ WKt,
    const u16* __restrict__ WVt, u16* __restrict__ M_all, u16* __restrict__ U_all) {
    __shared__ u16 Cst[256 * 64];
    const int f0 = blockIdx.x * 64, n = blockIdx.y, which = blockIdx.z;
    const u16* vec = fiveb + ((which ? 4 : 1) * HH + n) * TT * DHH;
    const u16* W = (which ? WVt : WKt) + (size_t)n * 262144;
    u16* out = (which ? U_all : M_all) + (size_t)n * 1048576;
    const int tid = threadIdx.x, w = tid >> 6, lane = tid & 63;
    const int quad = lane >> 4, l15 = lane & 15;

    bf16x8 bf[4][2];
#pragma unroll
    for (int nt = 0; nt < 4; ++nt) {
        bf[nt][0] = *(const bf16x8*)&W[(size_t)(f0 + nt * 16 + l15) * 64 + quad * 8];
        bf[nt][1] = *(const bf16x8*)&W[(size_t)(f0 + nt * 16 + l15) * 64 + 32 + quad * 8];
    }
    f32x4 acc[4][4];
#pragma unroll
    for (int mt = 0; mt < 4; ++mt) {
        int trow = w * 64 + mt * 16 + l15;
        bf16x8 a0 = *(const bf16x8*)&vec[trow * 64 + quad * 8];
        bf16x8 a1 = *(const bf16x8*)&vec[trow * 64 + 32 + quad * 8];
#pragma unroll
        for (int nt = 0; nt < 4; ++nt) {
            f32x4 c = {0.f, 0.f, 0.f, 0.f};
            c = MFMA(a0, bf[nt][0], c, 0, 0, 0);
            c = MFMA(a1, bf[nt][1], c, 0, 0, 0);
            acc[mt][nt] = c;
        }
    }
#pragma unroll
    for (int mt = 0; mt < 4; ++mt)
#pragma unroll
        for (int nt = 0; nt < 4; ++nt)
#pragma unroll
            for (int r = 0; r < 4; ++r)
                Cst[(w * 64 + mt * 16 + quad * 4 + r) * 64 + nt * 16 + l15] = f2bf(acc[mt][nt][r]);
    __syncthreads();
    const uint4* src = (const uint4*)&Cst[tid * 64];
    uint4* dst = (uint4*)(out + (size_t)tid * 4096 + f0);
#pragma unroll
    for (int i = 0; i < 8; ++i) dst[i] = src[i];
}

// ---------------- K4: fused trilinear attention — private Z slices, no atomics
// grid 512 flat: n = b&7 (XCD pinning), j = b>>3 in [0,64) -> (qt, t-range), balanced.
__global__ __launch_bounds__(256, 6) void main_kernel(
    const u16* __restrict__ fiveb, const u16* __restrict__ v1T,
    const u16* __restrict__ M_all, const u16* __restrict__ U_all,
    float* __restrict__ Zpart, float* __restrict__ Lpart) {
    __shared__ u16 QMb[64 * 72];
    __shared__ u16 Pb[64 * 72];
    const int tid = threadIdx.x;
    const int b = blockIdx.x;
    const int n = b & 7, j = b >> 3;
    int qt, t0, cnt;
    if (j < 3)       { qt = 0; if (j == 0) { t0 = 0; cnt = 22; } else { t0 = 22 + (j - 1) * 21; cnt = 21; } }
    else if (j < 13) { qt = 1; int i = j - 3;  if (i < 8)  { t0 = i * 13; cnt = 13; } else { t0 = 104 + (i - 8) * 12; cnt = 12; } }
    else if (j < 32) { qt = 2; int i = j - 13; if (i < 2)  { t0 = i * 11; cnt = 11; } else { t0 = 22 + (i - 2) * 10; cnt = 10; } }
    else             { qt = 3; int i = j - 32; t0 = i * 8; cnt = 8; }
    const int q0 = qt * 64, nP = qt + 1;

    const u16* k1g = fiveb + (0 * 8 + n) * 256 * 64;
    const u16* qg  = fiveb + (2 * 8 + n) * 256 * 64;
    const u16* v1g = v1T + n * 64 * 256;
    const u16* Mg = M_all + (size_t)(n * 256) * 4096;
    const u16* Ug = U_all + (size_t)(n * 256) * 4096;

    const int w = tid >> 6, lane = tid & 63, quad = lane >> 4, l15 = lane & 15;
    const int r0 = w * 16;

    // q A-fragments: wave-local, loop-invariant -> registers
    const bf16x8 qa0 = *(const bf16x8*)&qg[(q0 + r0 + l15) * 64 + quad * 8];
    const bf16x8 qa1 = *(const bf16x8*)&qg[(q0 + r0 + l15) * 64 + 32 + quad * 8];

    f32x4 Zc[4];
#pragma unroll
    for (int nt = 0; nt < 4; ++nt) Zc[nt] = (f32x4){0.f, 0.f, 0.f, 0.f};
    float lsum = 0.f;

    for (int tt = 0; tt < cnt; ++tt) {
        const int t = t0 + tt;
        const u16* Mt = Mg + (size_t)t * 4096;
        const u16* Ut = Ug + (size_t)t * 4096;

        // QM = q . M_t^T (B streamed from global/L2), roundtrip to A-layout
#pragma unroll
        for (int nt = 0; nt < 4; ++nt) {
            bf16x8 b0 = *(const bf16x8*)&Mt[(nt * 16 + l15) * 64 + quad * 8];
            bf16x8 b1 = *(const bf16x8*)&Mt[(nt * 16 + l15) * 64 + 32 + quad * 8];
            f32x4 c = {0.f, 0.f, 0.f, 0.f};
            c = MFMA(qa0, b0, c, 0, 0, 0);
            c = MFMA(qa1, b1, c, 0, 0, 0);
#pragma unroll
            for (int r = 0; r < 4; ++r)
                QMb[(r0 + quad * 4 + r) * 72 + nt * 16 + l15] = f2bf(c[r]);
        }
        const bf16x8 qma0 = *(const bf16x8*)&QMb[(r0 + l15) * 72 + quad * 8];
        const bf16x8 qma1 = *(const bf16x8*)&QMb[(r0 + l15) * 72 + 32 + quad * 8];

        f32x4 Gc[4];
#pragma unroll
        for (int nt = 0; nt < 4; ++nt) Gc[nt] = (f32x4){0.f, 0.f, 0.f, 0.f};

        for (int pt = 0; pt < nP; ++pt) {
            // S = QM . k1^T ; mask+exp -> Pb
#pragma unroll
            for (int nt = 0; nt < 4; ++nt) {
                bf16x8 b0 = *(const bf16x8*)&k1g[(pt * 64 + nt * 16 + l15) * 64 + quad * 8];
                bf16x8 b1 = *(const bf16x8*)&k1g[(pt * 64 + nt * 16 + l15) * 64 + 32 + quad * 8];
                f32x4 s = {0.f, 0.f, 0.f, 0.f};
                s = MFMA(qma0, b0, s, 0, 0, 0);
                s = MFMA(qma1, b1, s, 0, 0, 0);
                const int p = pt * 64 + nt * 16 + l15;
#pragma unroll
                for (int r = 0; r < 4; ++r) {
                    const int q = q0 + r0 + quad * 4 + r;
                    float wv = (p <= q && t <= q) ? __expf(s[r] * 0.015625f) : 0.f;
                    Pb[(r0 + quad * 4 + r) * 72 + nt * 16 + l15] = f2bf(wv);
                }
            }
            // P A-fragments (also provide the L row partial sums)
            bf16x8 pa0 = *(const bf16x8*)&Pb[(r0 + l15) * 72 + quad * 8];
            bf16x8 pa1 = *(const bf16x8*)&Pb[(r0 + l15) * 72 + 32 + quad * 8];
            lsum += sum8v(pa0) + sum8v(pa1);
            // G += P . v1tile
#pragma unroll
            for (int nt = 0; nt < 4; ++nt) {
                bf16x8 b0 = *(const bf16x8*)&v1g[(nt * 16 + l15) * 256 + pt * 64 + quad * 8];
                bf16x8 b1 = *(const bf16x8*)&v1g[(nt * 16 + l15) * 256 + pt * 64 + 32 + quad * 8];
                Gc[nt] = MFMA(pa0, b0, Gc[nt], 0, 0, 0);
                Gc[nt] = MFMA(pa1, b1, Gc[nt], 0, 0, 0);
            }
        }
        // Z += G . U_t  (G roundtrip via Pb, wave-local)
#pragma unroll
        for (int nt = 0; nt < 4; ++nt)
#pragma unroll
            for (int r = 0; r < 4; ++r)
                Pb[(r0 + quad * 4 + r) * 72 + nt * 16 + l15] = f2bf(Gc[nt][r]);
        bf16x8 ga0 = *(const bf16x8*)&Pb[(r0 + l15) * 72 + quad * 8];
        bf16x8 ga1 = *(const bf16x8*)&Pb[(r0 + l15) * 72 + 32 + quad * 8];
#pragma unroll
        for (int nt = 0; nt < 4; ++nt) {
            bf16x8 b0 = *(const bf16x8*)&Ut[(nt * 16 + l15) * 64 + quad * 8];
            bf16x8 b1 = *(const bf16x8*)&Ut[(nt * 16 + l15) * 64 + 32 + quad * 8];
            Zc[nt] = MFMA(ga0, b0, Zc[nt], 0, 0, 0);
            Zc[nt] = MFMA(ga1, b1, Zc[nt], 0, 0, 0);
        }
    }

    // flush: private slice, plain coalesced stores
    float* zbase = Zpart + (size_t)b * 4096;
#pragma unroll
    for (int nt = 0; nt < 4; ++nt)
#pragma unroll
        for (int r = 0; r < 4; ++r)
            zbase[(r0 + quad * 4 + r) * 64 + nt * 16 + l15] = Zc[nt][r];
    lsum += __shfl_xor(lsum, 16);
    lsum += __shfl_xor(lsum, 32);
    if (quad == 0) Lpart[b * 64 + r0 + l15] = lsum;
}

// ---------------- K5: zn[t][h*64+e] = bf16( sum_j Zpart / sum_j Lpart )
__global__ __launch_bounds__(256) void zn_kernel(
    const float* __restrict__ Zpart, const float* __restrict__ Lpart, u16* __restrict__ zn) {
    const int flat = (blockIdx.x * 256 + threadIdx.x) * 4;
    const int t = flat >> 9, he = flat & 511, h = he >> 6, e = he & 63;
    const int qt = t >> 6, qq = t & 63;
    int jb, je;
    if (qt == 0)      { jb = 0;  je = 3;  }
    else if (qt == 1) { jb = 3;  je = 13; }
    else if (qt == 2) { jb = 13; je = 32; }
    else              { jb = 32; je = 64; }
    float4 sz = {0.f, 0.f, 0.f, 0.f};
    float sl = 0.f;
    for (int j = jb; j < je; ++j) {
        const int bb = j * 8 + h;
        const float4 v = *(const float4*)(Zpart + (size_t)bb * 4096 + qq * 64 + e);
        sz.x += v.x; sz.y += v.y; sz.z += v.z; sz.w += v.w;
        sl += Lpart[bb * 64 + qq];
    }
    const float inv = 1.f / sl;
    __attribute__((aligned(8))) u16 t4[4];
    t4[0] = f2bf(sz.x * inv); t4[1] = f2bf(sz.y * inv);
    t4[2] = f2bf(sz.z * inv); t4[3] = f2bf(sz.w * inv);
    *(uint2*)(zn + flat) = *(uint2*)t4;
}

// ---------------- K6: out = zn @ Wot^T + b_out (fp32 out), MFMA
__global__ __launch_bounds__(256) void out_mfma(
    const u16* __restrict__ zn, const u16* __restrict__ Wot,
    const float* __restrict__ b_out, float* __restrict__ out) {
    const int tid = threadIdx.x, w = tid >> 6, lane = tid & 63;
    const int quad = lane >> 4, l15 = lane & 15;
    const int m0 = blockIdx.x * 64 + w * 16;
    const int c0 = blockIdx.y * 64;
    f32x4 acc[4];
#pragma unroll
    for (int nt = 0; nt < 4; ++nt) acc[nt] = (f32x4){0.f, 0.f, 0.f, 0.f};
    for (int kc = 0; kc < 16; ++kc) {
        bf16x8 a = *(const bf16x8*)&zn[(size_t)(m0 + l15) * 512 + kc * 32 + quad * 8];
#pragma unroll
        for (int nt = 0; nt < 4; ++nt) {
            bf16x8 b = *(const bf16x8*)&Wot[(size_t)(c0 + nt * 16 + l15) * 512 + kc * 32 + quad * 8];
            acc[nt] = MFMA(a, b, acc[nt], 0, 0, 0);
        }
    }
#pragma unroll
    for (int nt = 0; nt < 4; ++nt) {
        const int col = c0 + nt * 16 + l15;
        const float b = b_out[col];
#pragma unroll
        for (int r = 0; r < 4; ++r)
            out[(size_t)(m0 + quad * 4 + r) * 512 + col] = acc[nt][r] + b;
    }
}

extern "C" void kernel_launch(void* const* d_in, const int* in_sizes, int n_in,
                              void* d_out, int out_size, void* d_ws, size_t ws_size,
                              hipStream_t stream) {
    const float* x       = (const float*)d_in[0];
    const float* W_kkqvv = (const float*)d_in[1];
    const float* b_kkqvv = (const float*)d_in[2];
    const float* W_Kq    = (const float*)d_in[3];
    const float* W_Vq    = (const float*)d_in[4];
    const float* W_out   = (const float*)d_in[5];
    const float* b_out   = (const float*)d_in[6];

    char* base = (char*)d_ws;
    u16*   fiveb = (u16*)base;                      // 1,310,720 B
    u16*   WKt   = (u16*)(base + 1843200);          // 4 MB
    u16*   WVt   = (u16*)(base + 6037504);          // 4 MB
    u16*   M_all = (u16*)(base + 10231808);         // 16 MB
    u16*   U_all = (u16*)(base + 27009024);         // 16 MB
    // aliases:
    float* Zpart = (float*)(base + 1843200);        // 8 MB over WKt+WVt (dead after mu_gemm); 512 slices
    u16*   Wt    = (u16*)(base + 10231808);         // dead after proj (over M_all)
    u16*   xb    = (u16*)(base + 12853248);
    u16*   Wot   = (u16*)(base + 43786240);         // 524,288 B
    u16*   v1T   = (u16*)(base + 44310528);         // 262,144 B
    u16*   zn    = (u16*)(base + 44572672);         // 262,144 B
    float* Lpart = (float*)(base + 44834816);       // 131,072 B (end ~44.97 MB)

    prep_kernel<<<392, 256, 0, stream>>>(W_kkqvv, W_out, x, Wt, Wot, xb);
    proj_mfma<<<dim3(4, 40), 256, 0, stream>>>(xb, Wt, b_kkqvv, fiveb, v1T);
    transpose_w<<<dim3(64, 8, 2), 256, 0, stream>>>(W_Kq, W_Vq, WKt, WVt);
    mu_gemm<<<dim3(64, 8, 2), 256, 0, stream>>>(fiveb, WKt, WVt, M_all, U_all);
    main_kernel<<<512, 256, 0, stream>>>(fiveb, v1T, M_all, U_all, Zpart, Lpart);
    zn_kernel<<<128, 256, 0, stream>>>(Zpart, Lpart, zn);
    out_mfma<<<dim3(4, 8), 256, 0, stream>>>(zn, Wot, b_out, (float*)d_out);
}

// Round 9
// 298.742 us; speedup vs baseline: 1.1233x; 1.0772x over previous
//
#include <hip/hip_runtime.h>

typedef unsigned short u16;
typedef unsigned int u32;
typedef __attribute__((ext_vector_type(8))) short bf16x8;
typedef __attribute__((ext_vector_type(4))) float f32x4;
#define MFMA __builtin_amdgcn_mfma_f32_16x16x32_bf16

#define TT 256
#define DD 512
#define HH 8
#define DHH 64
#define NC 2560   // 5*H*DH

__device__ __forceinline__ u16 f2bf(float f) {
    u32 x; __builtin_memcpy(&x, &f, 4);
    u32 r = (x + 0x7FFFu + ((x >> 16) & 1u)) >> 16;
    return (u16)r;
}
__device__ __forceinline__ void unpack2(u32 u, float& lo, float& hi) {
    u32 l = u << 16, h = u & 0xFFFF0000u;
    __builtin_memcpy(&lo, &l, 4); __builtin_memcpy(&hi, &h, 4);
}
__device__ __forceinline__ float sum8v(bf16x8 v) {
    uint4 u; __builtin_memcpy(&u, &v, 16);
    float f[8];
    unpack2(u.x, f[0], f[1]); unpack2(u.y, f[2], f[3]);
    unpack2(u.z, f[4], f[5]); unpack2(u.w, f[6], f[7]);
    return ((f[0]+f[1])+(f[2]+f[3]))+((f[4]+f[5])+(f[6]+f[7]));
}

// ---------------- K0: prep — Wt = bf16(W_kkqvv)^T, Wot = bf16(W_out)^T, xb = bf16(x)
__global__ __launch_bounds__(256) void prep_kernel(
    const float* __restrict__ W1, const float* __restrict__ Wo,
    const float* __restrict__ x,
    u16* __restrict__ Wt, u16* __restrict__ Wot, u16* __restrict__ xb) {
    __shared__ float S[64 * 65];
    const int bid = blockIdx.x, tid = threadIdx.x;
    if (bid < 384) {
        int tc, tr, Cw;
        const float* src; u16* dst;
        if (bid < 320) { tc = bid % 40; tr = bid / 40; src = W1; dst = Wt;  Cw = 2560; }
        else { int b2 = bid - 320; tc = b2 % 8; tr = b2 / 8; src = Wo; dst = Wot; Cw = 512; }
        {
            int X = tid >> 2, c0 = (tid & 3) * 16;
            const float4* s4 = (const float4*)(src + (size_t)(tr * 64 + X) * Cw + tc * 64 + c0);
            float4 v0 = s4[0], v1 = s4[1], v2 = s4[2], v3 = s4[3];
            float* d = &S[X * 65 + c0];
            d[0]=v0.x; d[1]=v0.y; d[2]=v0.z; d[3]=v0.w;
            d[4]=v1.x; d[5]=v1.y; d[6]=v1.z; d[7]=v1.w;
            d[8]=v2.x; d[9]=v2.y; d[10]=v2.z; d[11]=v2.w;
            d[12]=v3.x; d[13]=v3.y; d[14]=v3.z; d[15]=v3.w;
        }
        __syncthreads();
        {
            int Y = tid >> 2, x0 = (tid & 3) * 16;
            __attribute__((aligned(16))) u16 tmp[16];
#pragma unroll
            for (int xx = 0; xx < 16; ++xx) tmp[xx] = f2bf(S[(x0 + xx) * 65 + Y]);
            u16* o = dst + (size_t)(tc * 64 + Y) * 512 + tr * 64 + x0;
            *(uint4*)o = *(uint4*)tmp;
            *(uint4*)(o + 8) = *(uint4*)(tmp + 8);
        }
    } else {
        int b3 = bid - 384;            // 8 blocks cast x -> xb
        size_t base = (size_t)(b3 * 256 + tid) * 64;
        const float4* s = (const float4*)(x + base);
#pragma unroll
        for (int i = 0; i < 8; ++i) {
            float4 lo = s[2 * i], hi = s[2 * i + 1];
            __attribute__((aligned(16))) u16 t8[8];
            t8[0]=f2bf(lo.x); t8[1]=f2bf(lo.y); t8[2]=f2bf(lo.z); t8[3]=f2bf(lo.w);
            t8[4]=f2bf(hi.x); t8[5]=f2bf(hi.y); t8[6]=f2bf(hi.z); t8[7]=f2bf(hi.w);
            ((uint4*)(xb + base))[i] = *(uint4*)t8;
        }
    }
}

// ---------------- K1: proj MFMA: proj = xb @ Wt^T + b -> fiveb (v=3 -> v1T transposed)
__global__ __launch_bounds__(256) void proj_mfma(
    const u16* __restrict__ xb, const u16* __restrict__ Wt,
    const float* __restrict__ bias, u16* __restrict__ fiveb, u16* __restrict__ v1T) {
    const int tid = threadIdx.x, w = tid >> 6, lane = tid & 63;
    const int quad = lane >> 4, l15 = lane & 15;
    const int m0 = blockIdx.x * 64 + w * 16;
    const int c0 = blockIdx.y * 64;
    f32x4 acc[4];
#pragma unroll
    for (int nt = 0; nt < 4; ++nt) acc[nt] = (f32x4){0.f, 0.f, 0.f, 0.f};
    for (int kc = 0; kc < 16; ++kc) {
        bf16x8 a = *(const bf16x8*)&xb[(size_t)(m0 + l15) * 512 + kc * 32 + quad * 8];
#pragma unroll
        for (int nt = 0; nt < 4; ++nt) {
            bf16x8 b = *(const bf16x8*)&Wt[(size_t)(c0 + nt * 16 + l15) * 512 + kc * 32 + quad * 8];
            acc[nt] = MFMA(a, b, acc[nt], 0, 0, 0);
        }
    }
#pragma unroll
    for (int nt = 0; nt < 4; ++nt) {
        const int col = c0 + nt * 16 + l15;
        const float b = bias[col];
        const int v = col >> 9, h = (col >> 6) & 7, e = col & 63;
#pragma unroll
        for (int r = 0; r < 4; ++r) {
            const int t = m0 + quad * 4 + r;
            u16 val = f2bf(acc[nt][r] + b);
            if (v == 3) v1T[(h * 64 + e) * 256 + t] = val;
            else        fiveb[((v * 8 + h) * 256 + t) * 64 + e] = val;
        }
    }
}

// ---------------- K2: transpose weights to K-contiguous bf16
__global__ __launch_bounds__(256) void transpose_w(
    const float* __restrict__ WK, const float* __restrict__ WV,
    u16* __restrict__ WKt, u16* __restrict__ WVt) {
    __shared__ float S[64 * 65];
    const int outer = blockIdx.x, n = blockIdx.y, which = blockIdx.z;
    const float* in = (which ? WV : WK) + ((size_t)(n * 64 + outer)) * 4096;
    u16* outbase = (which ? WVt : WKt) + (size_t)n * 262144;
    const int tid = threadIdx.x;
    {
        int X = tid >> 2, c0 = (tid & 3) * 16;
        const float4* s = (const float4*)(in + X * 64 + c0);
        float4 v0 = s[0], v1 = s[1], v2 = s[2], v3 = s[3];
        float* d = &S[X * 65 + c0];
        d[0]=v0.x; d[1]=v0.y; d[2]=v0.z; d[3]=v0.w;
        d[4]=v1.x; d[5]=v1.y; d[6]=v1.z; d[7]=v1.w;
        d[8]=v2.x; d[9]=v2.y; d[10]=v2.z; d[11]=v2.w;
        d[12]=v3.x; d[13]=v3.y; d[14]=v3.z; d[15]=v3.w;
    }
    __syncthreads();
    {
        int Y = tid >> 2, x0 = (tid & 3) * 16;
        __attribute__((aligned(16))) u16 tmp[16];
#pragma unroll
        for (int xx = 0; xx < 16; ++xx) tmp[xx] = f2bf(S[(x0 + xx) * 65 + Y]);
        size_t strideY = which ? 4096 : 64;
        size_t strideO = which ? 64 : 4096;
        u16* d = outbase + (size_t)Y * strideY + (size_t)outer * strideO + x0;
        *(uint4*)d = *(uint4*)tmp;
        *(uint4*)(d + 8) = *(uint4*)(tmp + 8);
    }
}

// ---------------- K3: M_all[n][t][f] = sum_j k2[t,j]*WKt[n][f][j]  (U analog)
__global__ __launch_bounds__(256, 1) void mu_gemm(
    const u16* __restrict__ fiveb, const u16* __restrict__ WKt,
    const u16* __restrict__ WVt, u16* __restrict__ M_all, u16* __restrict__ U_all) {
    __shared__ u16 Cst[256 * 64];
    const int f0 = blockIdx.x * 64, n = blockIdx.y, which = blockIdx.z;
    const u16* vec = fiveb + ((which ? 4 : 1) * HH + n) * TT * DHH;
    const u16* W = (which ? WVt : WKt) + (size_t)n * 262144;
    u16* out = (which ? U_all : M_all) + (size_t)n * 1048576;
    const int tid = threadIdx.x, w = tid >> 6, lane = tid & 63;
    const int quad = lane >> 4, l15 = lane & 15;

    bf16x8 bf[4][2];
#pragma unroll
    for (int nt = 0; nt < 4; ++nt) {
        bf[nt][0] = *(const bf16x8*)&W[(size_t)(f0 + nt * 16 + l15) * 64 + quad * 8];
        bf[nt][1] = *(const bf16x8*)&W[(size_t)(f0 + nt * 16 + l15) * 64 + 32 + quad * 8];
    }
    f32x4 acc[4][4];
#pragma unroll
    for (int mt = 0; mt < 4; ++mt) {
        int trow = w * 64 + mt * 16 + l15;
        bf16x8 a0 = *(const bf16x8*)&vec[trow * 64 + quad * 8];
        bf16x8 a1 = *(const bf16x8*)&vec[trow * 64 + 32 + quad * 8];
#pragma unroll
        for (int nt = 0; nt < 4; ++nt) {
            f32x4 c = {0.f, 0.f, 0.f, 0.f};
            c = MFMA(a0, bf[nt][0], c, 0, 0, 0);
            c = MFMA(a1, bf[nt][1], c, 0, 0, 0);
            acc[mt][nt] = c;
        }
    }
#pragma unroll
    for (int mt = 0; mt < 4; ++mt)
#pragma unroll
        for (int nt = 0; nt < 4; ++nt)
#pragma unroll
            for (int r = 0; r < 4; ++r)
                Cst[(w * 64 + mt * 16 + quad * 4 + r) * 64 + nt * 16 + l15] = f2bf(acc[mt][nt][r]);
    __syncthreads();
    const uint4* src = (const uint4*)&Cst[tid * 64];
    uint4* dst = (uint4*)(out + (size_t)tid * 4096 + f0);
#pragma unroll
    for (int i = 0; i < 8; ++i) dst[i] = src[i];
}

// ---------------- K4: fused trilinear attention — no atomics, no spills, 50% occ
// grid 1016 flat: n = b&7 (XCD pinning), j = b>>3 in [0,127) -> balanced (qt, t-range).
__global__ __launch_bounds__(256, 4) void main_kernel(
    const u16* __restrict__ fiveb, const u16* __restrict__ v1T,
    const u16* __restrict__ M_all, const u16* __restrict__ U_all,
    u16* __restrict__ Zpart, float* __restrict__ Lpart) {
    __shared__ u16 QMb[64 * 72];
    __shared__ u16 Pb[2 * 64 * 72];
    const int tid = threadIdx.x;
    const int b = blockIdx.x;
    const int n = b & 7, j = b >> 3;
    int qt, t0, cnt;
    if (j < 6)       { qt = 0; int i = j;      cnt = (i < 4) ? 11 : 10; t0 = (i < 4) ? 11 * i : 44 + 10 * (i - 4); }
    else if (j < 25) { qt = 1; int i = j - 6;  cnt = (i < 14) ? 7 : 6;  t0 = (i < 14) ? 7 * i : 98 + 6 * (i - 14); }
    else if (j < 63) { qt = 2; int i = j - 25; cnt = (i < 2) ? 6 : 5;   t0 = (i < 2) ? 6 * i : 12 + 5 * (i - 2); }
    else             { qt = 3; int i = j - 63; cnt = 4;                 t0 = 4 * i; }
    const int q0 = qt * 64, nP = qt + 1;

    const u16* k1g = fiveb + (0 * 8 + n) * 256 * 64;
    const u16* qg  = fiveb + (2 * 8 + n) * 256 * 64;
    const u16* v1g = v1T + n * 64 * 256;
    const u16* Mg = M_all + (size_t)(n * 256) * 4096;
    const u16* Ug = U_all + (size_t)(n * 256) * 4096;

    const int w = tid >> 6, lane = tid & 63, quad = lane >> 4, l15 = lane & 15;
    const int r0 = w * 16;

    // q A-fragments: wave-local, loop-invariant -> registers
    const bf16x8 qa0 = *(const bf16x8*)&qg[(q0 + r0 + l15) * 64 + quad * 8];
    const bf16x8 qa1 = *(const bf16x8*)&qg[(q0 + r0 + l15) * 64 + 32 + quad * 8];

    f32x4 Zc[4];
#pragma unroll
    for (int nt = 0; nt < 4; ++nt) Zc[nt] = (f32x4){0.f, 0.f, 0.f, 0.f};
    float lsum = 0.f;

    for (int tt = 0; tt < cnt; ++tt) {
        const int t = t0 + tt;
        const u16* Mt = Mg + (size_t)t * 4096;
        const u16* Ut = Ug + (size_t)t * 4096;

        // QM = q . M_t^T (B streamed from global/L2), roundtrip to A-layout
#pragma unroll
        for (int nt = 0; nt < 4; ++nt) {
            bf16x8 b0 = *(const bf16x8*)&Mt[(nt * 16 + l15) * 64 + quad * 8];
            bf16x8 b1 = *(const bf16x8*)&Mt[(nt * 16 + l15) * 64 + 32 + quad * 8];
            f32x4 c = {0.f, 0.f, 0.f, 0.f};
            c = MFMA(qa0, b0, c, 0, 0, 0);
            c = MFMA(qa1, b1, c, 0, 0, 0);
#pragma unroll
            for (int r = 0; r < 4; ++r)
                QMb[(r0 + quad * 4 + r) * 72 + nt * 16 + l15] = f2bf(c[r]);
        }
        const bf16x8 qma0 = *(const bf16x8*)&QMb[(r0 + l15) * 72 + quad * 8];
        const bf16x8 qma1 = *(const bf16x8*)&QMb[(r0 + l15) * 72 + 32 + quad * 8];

        f32x4 Gc[4];
#pragma unroll
        for (int nt = 0; nt < 4; ++nt) Gc[nt] = (f32x4){0.f, 0.f, 0.f, 0.f};

        for (int pt = 0; pt < nP; ++pt) {
            u16* Pbc = Pb + (pt & 1) * 4608;   // alternate buffers: decouple pt chain
            // S = QM . k1^T ; mask+exp -> Pbc
#pragma unroll
            for (int nt = 0; nt < 4; ++nt) {
                bf16x8 b0 = *(const bf16x8*)&k1g[(pt * 64 + nt * 16 + l15) * 64 + quad * 8];
                bf16x8 b1 = *(const bf16x8*)&k1g[(pt * 64 + nt * 16 + l15) * 64 + 32 + quad * 8];
                f32x4 s = {0.f, 0.f, 0.f, 0.f};
                s = MFMA(qma0, b0, s, 0, 0, 0);
                s = MFMA(qma1, b1, s, 0, 0, 0);
                const int p = pt * 64 + nt * 16 + l15;
#pragma unroll
                for (int r = 0; r < 4; ++r) {
                    const int q = q0 + r0 + quad * 4 + r;
                    float wv = (p <= q && t <= q) ? __expf(s[r] * 0.015625f) : 0.f;
                    Pbc[(r0 + quad * 4 + r) * 72 + nt * 16 + l15] = f2bf(wv);
                }
            }
            // P A-fragments (also provide the L row partial sums)
            bf16x8 pa0 = *(const bf16x8*)&Pbc[(r0 + l15) * 72 + quad * 8];
            bf16x8 pa1 = *(const bf16x8*)&Pbc[(r0 + l15) * 72 + 32 + quad * 8];
            lsum += sum8v(pa0) + sum8v(pa1);
            // G += P . v1tile
#pragma unroll
            for (int nt = 0; nt < 4; ++nt) {
                bf16x8 b0 = *(const bf16x8*)&v1g[(nt * 16 + l15) * 256 + pt * 64 + quad * 8];
                bf16x8 b1 = *(const bf16x8*)&v1g[(nt * 16 + l15) * 256 + pt * 64 + 32 + quad * 8];
                Gc[nt] = MFMA(pa0, b0, Gc[nt], 0, 0, 0);
                Gc[nt] = MFMA(pa1, b1, Gc[nt], 0, 0, 0);
            }
        }
        // Z += G . U_t  (G roundtrip via Pb, wave-local)
#pragma unroll
        for (int nt = 0; nt < 4; ++nt)
#pragma unroll
            for (int r = 0; r < 4; ++r)
                Pb[(r0 + quad * 4 + r) * 72 + nt * 16 + l15] = f2bf(Gc[nt][r]);
        bf16x8 ga0 = *(const bf16x8*)&Pb[(r0 + l15) * 72 + quad * 8];
        bf16x8 ga1 = *(const bf16x8*)&Pb[(r0 + l15) * 72 + 32 + quad * 8];
#pragma unroll
        for (int nt = 0; nt < 4; ++nt) {
            bf16x8 b0 = *(const bf16x8*)&Ut[(nt * 16 + l15) * 64 + quad * 8];
            bf16x8 b1 = *(const bf16x8*)&Ut[(nt * 16 + l15) * 64 + 32 + quad * 8];
            Zc[nt] = MFMA(ga0, b0, Zc[nt], 0, 0, 0);
            Zc[nt] = MFMA(ga1, b1, Zc[nt], 0, 0, 0);
        }
    }

    // flush: bf16 via wave-local LDS strip -> coalesced uint4 stores
#pragma unroll
    for (int nt = 0; nt < 4; ++nt)
#pragma unroll
        for (int r = 0; r < 4; ++r)
            Pb[(r0 + quad * 4 + r) * 72 + nt * 16 + l15] = f2bf(Zc[nt][r]);
    {
        const int row = r0 + (lane >> 2), cc = (lane & 3) * 16;
        uint4 z0 = *(const uint4*)&Pb[row * 72 + cc];
        uint4 z1 = *(const uint4*)&Pb[row * 72 + cc + 8];
        uint4* d = (uint4*)(Zpart + (size_t)b * 4096 + row * 64 + cc);
        d[0] = z0; d[1] = z1;
    }
    lsum += __shfl_xor(lsum, 16);
    lsum += __shfl_xor(lsum, 32);
    if (quad == 0) Lpart[b * 64 + r0 + l15] = lsum;
}

// ---------------- K5: zn[t][h*64+e] = bf16( sum_j Zpart / sum_j Lpart )
__global__ __launch_bounds__(256) void zn_kernel(
    const u16* __restrict__ Zpart, const float* __restrict__ Lpart, u16* __restrict__ zn) {
    const int flat = (blockIdx.x * 256 + threadIdx.x) * 4;
    const int t = flat >> 9, he = flat & 511, h = he >> 6, e = he & 63;
    const int qt = t >> 6, qq = t & 63;
    int jb, je;
    if (qt == 0)      { jb = 0;  je = 6;   }
    else if (qt == 1) { jb = 6;  je = 25;  }
    else if (qt == 2) { jb = 25; je = 63;  }
    else              { jb = 63; je = 127; }
    float4 sz = {0.f, 0.f, 0.f, 0.f};
    float sl = 0.f;
    for (int j = jb; j < je; ++j) {
        const int bb = j * 8 + h;
        uint2 zv = *(const uint2*)(Zpart + (size_t)bb * 4096 + qq * 64 + e);
        float f0, f1, f2, f3;
        unpack2(zv.x, f0, f1); unpack2(zv.y, f2, f3);
        sz.x += f0; sz.y += f1; sz.z += f2; sz.w += f3;
        sl += Lpart[bb * 64 + qq];
    }
    const float inv = 1.f / sl;
    __attribute__((aligned(8))) u16 t4[4];
    t4[0] = f2bf(sz.x * inv); t4[1] = f2bf(sz.y * inv);
    t4[2] = f2bf(sz.z * inv); t4[3] = f2bf(sz.w * inv);
    *(uint2*)(zn + flat) = *(uint2*)t4;
}

// ---------------- K6: out = zn @ Wot^T + b_out (fp32 out), MFMA
__global__ __launch_bounds__(256) void out_mfma(
    const u16* __restrict__ zn, const u16* __restrict__ Wot,
    const float* __restrict__ b_out, float* __restrict__ out) {
    const int tid = threadIdx.x, w = tid >> 6, lane = tid & 63;
    const int quad = lane >> 4, l15 = lane & 15;
    const int m0 = blockIdx.x * 64 + w * 16;
    const int c0 = blockIdx.y * 64;
    f32x4 acc[4];
#pragma unroll
    for (int nt = 0; nt < 4; ++nt) acc[nt] = (f32x4){0.f, 0.f, 0.f, 0.f};
    for (int kc = 0; kc < 16; ++kc) {
        bf16x8 a = *(const bf16x8*)&zn[(size_t)(m0 + l15) * 512 + kc * 32 + quad * 8];
#pragma unroll
        for (int nt = 0; nt < 4; ++nt) {
            bf16x8 b = *(const bf16x8*)&Wot[(size_t)(c0 + nt * 16 + l15) * 512 + kc * 32 + quad * 8];
            acc[nt] = MFMA(a, b, acc[nt], 0, 0, 0);
        }
    }
#pragma unroll
    for (int nt = 0; nt < 4; ++nt) {
        const int col = c0 + nt * 16 + l15;
        const float b = b_out[col];
#pragma unroll
        for (int r = 0; r < 4; ++r)
            out[(size_t)(m0 + quad * 4 + r) * 512 + col] = acc[nt][r] + b;
    }
}

extern "C" void kernel_launch(void* const* d_in, const int* in_sizes, int n_in,
                              void* d_out, int out_size, void* d_ws, size_t ws_size,
                              hipStream_t stream) {
    const float* x       = (const float*)d_in[0];
    const float* W_kkqvv = (const float*)d_in[1];
    const float* b_kkqvv = (const float*)d_in[2];
    const float* W_Kq    = (const float*)d_in[3];
    const float* W_Vq    = (const float*)d_in[4];
    const float* W_out   = (const float*)d_in[5];
    const float* b_out   = (const float*)d_in[6];

    char* base = (char*)d_ws;
    u16*   fiveb = (u16*)base;                      // 1,310,720 B
    u16*   WKt   = (u16*)(base + 1843200);          // 4 MB
    u16*   WVt   = (u16*)(base + 6037504);          // 4 MB
    u16*   M_all = (u16*)(base + 10231808);         // 16 MB
    u16*   U_all = (u16*)(base + 27009024);         // 16 MB
    // aliases:
    u16*   Zpart = (u16*)(base + 1843200);          // 8.32 MB over WKt+WVt (dead after mu_gemm); 1016 slices bf16
    u16*   Wt    = (u16*)(base + 10231808);         // dead after proj (over M_all)
    u16*   xb    = (u16*)(base + 12853248);
    u16*   Wot   = (u16*)(base + 43786240);         // 524,288 B
    u16*   v1T   = (u16*)(base + 44310528);         // 262,144 B
    u16*   zn    = (u16*)(base + 44572672);         // 262,144 B
    float* Lpart = (float*)(base + 44834816);       // 260,096 B (end ~45.1 MB)

    prep_kernel<<<392, 256, 0, stream>>>(W_kkqvv, W_out, x, Wt, Wot, xb);
    proj_mfma<<<dim3(4, 40), 256, 0, stream>>>(xb, Wt, b_kkqvv, fiveb, v1T);
    transpose_w<<<dim3(64, 8, 2), 256, 0, stream>>>(W_Kq, W_Vq, WKt, WVt);
    mu_gemm<<<dim3(64, 8, 2), 256, 0, stream>>>(fiveb, WKt, WVt, M_all, U_all);
    main_kernel<<<1016, 256, 0, stream>>>(fiveb, v1T, M_all, U_all, Zpart, Lpart);
    zn_kernel<<<128, 256, 0, stream>>>(Zpart, Lpart, zn);
    out_mfma<<<dim3(4, 8), 256, 0, stream>>>(zn, Wot, b_out, (float*)d_out);
}

// Round 10
// 235.224 us; speedup vs baseline: 1.4267x; 1.2700x over previous
//
#include <hip/hip_runtime.h>

typedef unsigned short u16;
typedef unsigned int u32;
typedef __attribute__((ext_vector_type(8))) short bf16x8;
typedef __attribute__((ext_vector_type(4))) float f32x4;
#define MFMA __builtin_amdgcn_mfma_f32_16x16x32_bf16

#define TT 256
#define DD 512
#define HH 8
#define DHH 64
#define NC 2560   // 5*H*DH

__device__ __forceinline__ u16 f2bf(float f) {
    u32 x; __builtin_memcpy(&x, &f, 4);
    u32 r = (x + 0x7FFFu + ((x >> 16) & 1u)) >> 16;
    return (u16)r;
}
__device__ __forceinline__ void unpack2(u32 u, float& lo, float& hi) {
    u32 l = u << 16, h = u & 0xFFFF0000u;
    __builtin_memcpy(&lo, &l, 4); __builtin_memcpy(&hi, &h, 4);
}
__device__ __forceinline__ float sum8v(bf16x8 v) {
    uint4 u; __builtin_memcpy(&u, &v, 16);
    float f[8];
    unpack2(u.x, f[0], f[1]); unpack2(u.y, f[2], f[3]);
    unpack2(u.z, f[4], f[5]); unpack2(u.w, f[6], f[7]);
    return ((f[0]+f[1])+(f[2]+f[3]))+((f[4]+f[5])+(f[6]+f[7]));
}

// ---------------- K0: prep — Wt = bf16(W_kkqvv)^T, Wot = bf16(W_out)^T, xb = bf16(x)
__global__ __launch_bounds__(256) void prep_kernel(
    const float* __restrict__ W1, const float* __restrict__ Wo,
    const float* __restrict__ x,
    u16* __restrict__ Wt, u16* __restrict__ Wot, u16* __restrict__ xb) {
    __shared__ float S[64 * 65];
    const int bid = blockIdx.x, tid = threadIdx.x;
    if (bid < 384) {
        int tc, tr, Cw;
        const float* src; u16* dst;
        if (bid < 320) { tc = bid % 40; tr = bid / 40; src = W1; dst = Wt;  Cw = 2560; }
        else { int b2 = bid - 320; tc = b2 % 8; tr = b2 / 8; src = Wo; dst = Wot; Cw = 512; }
        {
            int X = tid >> 2, c0 = (tid & 3) * 16;
            const float4* s4 = (const float4*)(src + (size_t)(tr * 64 + X) * Cw + tc * 64 + c0);
            float4 v0 = s4[0], v1 = s4[1], v2 = s4[2], v3 = s4[3];
            float* d = &S[X * 65 + c0];
            d[0]=v0.x; d[1]=v0.y; d[2]=v0.z; d[3]=v0.w;
            d[4]=v1.x; d[5]=v1.y; d[6]=v1.z; d[7]=v1.w;
            d[8]=v2.x; d[9]=v2.y; d[10]=v2.z; d[11]=v2.w;
            d[12]=v3.x; d[13]=v3.y; d[14]=v3.z; d[15]=v3.w;
        }
        __syncthreads();
        {
            int Y = tid >> 2, x0 = (tid & 3) * 16;
            __attribute__((aligned(16))) u16 tmp[16];
#pragma unroll
            for (int xx = 0; xx < 16; ++xx) tmp[xx] = f2bf(S[(x0 + xx) * 65 + Y]);
            u16* o = dst + (size_t)(tc * 64 + Y) * 512 + tr * 64 + x0;
            *(uint4*)o = *(uint4*)tmp;
            *(uint4*)(o + 8) = *(uint4*)(tmp + 8);
        }
    } else {
        int b3 = bid - 384;            // 8 blocks cast x -> xb
        size_t base = (size_t)(b3 * 256 + tid) * 64;
        const float4* s = (const float4*)(x + base);
#pragma unroll
        for (int i = 0; i < 8; ++i) {
            float4 lo = s[2 * i], hi = s[2 * i + 1];
            __attribute__((aligned(16))) u16 t8[8];
            t8[0]=f2bf(lo.x); t8[1]=f2bf(lo.y); t8[2]=f2bf(lo.z); t8[3]=f2bf(lo.w);
            t8[4]=f2bf(hi.x); t8[5]=f2bf(hi.y); t8[6]=f2bf(hi.z); t8[7]=f2bf(hi.w);
            ((uint4*)(xb + base))[i] = *(uint4*)t8;
        }
    }
}

// ---------------- K1: proj MFMA: proj = xb @ Wt^T + b -> fiveb (v=3 -> v1T transposed)
__global__ __launch_bounds__(256) void proj_mfma(
    const u16* __restrict__ xb, const u16* __restrict__ Wt,
    const float* __restrict__ bias, u16* __restrict__ fiveb, u16* __restrict__ v1T) {
    const int tid = threadIdx.x, w = tid >> 6, lane = tid & 63;
    const int quad = lane >> 4, l15 = lane & 15;
    const int m0 = blockIdx.x * 64 + w * 16;
    const int c0 = blockIdx.y * 64;
    f32x4 acc[4];
#pragma unroll
    for (int nt = 0; nt < 4; ++nt) acc[nt] = (f32x4){0.f, 0.f, 0.f, 0.f};
    for (int kc = 0; kc < 16; ++kc) {
        bf16x8 a = *(const bf16x8*)&xb[(size_t)(m0 + l15) * 512 + kc * 32 + quad * 8];
#pragma unroll
        for (int nt = 0; nt < 4; ++nt) {
            bf16x8 b = *(const bf16x8*)&Wt[(size_t)(c0 + nt * 16 + l15) * 512 + kc * 32 + quad * 8];
            acc[nt] = MFMA(a, b, acc[nt], 0, 0, 0);
        }
    }
#pragma unroll
    for (int nt = 0; nt < 4; ++nt) {
        const int col = c0 + nt * 16 + l15;
        const float b = bias[col];
        const int v = col >> 9, h = (col >> 6) & 7, e = col & 63;
#pragma unroll
        for (int r = 0; r < 4; ++r) {
            const int t = m0 + quad * 4 + r;
            u16 val = f2bf(acc[nt][r] + b);
            if (v == 3) v1T[(h * 64 + e) * 256 + t] = val;
            else        fiveb[((v * 8 + h) * 256 + t) * 64 + e] = val;
        }
    }
}

// ---------------- K2: transpose weights to K-contiguous bf16
__global__ __launch_bounds__(256) void transpose_w(
    const float* __restrict__ WK, const float* __restrict__ WV,
    u16* __restrict__ WKt, u16* __restrict__ WVt) {
    __shared__ float S[64 * 65];
    const int outer = blockIdx.x, n = blockIdx.y, which = blockIdx.z;
    const float* in = (which ? WV : WK) + ((size_t)(n * 64 + outer)) * 4096;
    u16* outbase = (which ? WVt : WKt) + (size_t)n * 262144;
    const int tid = threadIdx.x;
    {
        int X = tid >> 2, c0 = (tid & 3) * 16;
        const float4* s = (const float4*)(in + X * 64 + c0);
        float4 v0 = s[0], v1 = s[1], v2 = s[2], v3 = s[3];
        float* d = &S[X * 65 + c0];
        d[0]=v0.x; d[1]=v0.y; d[2]=v0.z; d[3]=v0.w;
        d[4]=v1.x; d[5]=v1.y; d[6]=v1.z; d[7]=v1.w;
        d[8]=v2.x; d[9]=v2.y; d[10]=v2.z; d[11]=v2.w;
        d[12]=v3.x; d[13]=v3.y; d[14]=v3.z; d[15]=v3.w;
    }
    __syncthreads();
    {
        int Y = tid >> 2, x0 = (tid & 3) * 16;
        __attribute__((aligned(16))) u16 tmp[16];
#pragma unroll
        for (int xx = 0; xx < 16; ++xx) tmp[xx] = f2bf(S[(x0 + xx) * 65 + Y]);
        size_t strideY = which ? 4096 : 64;
        size_t strideO = which ? 64 : 4096;
        u16* d = outbase + (size_t)Y * strideY + (size_t)outer * strideO + x0;
        *(uint4*)d = *(uint4*)tmp;
        *(uint4*)(d + 8) = *(uint4*)(tmp + 8);
    }
}

// ---------------- K3: M_all[n][t][f] = sum_j k2[t,j]*WKt[n][f][j]  (U analog)
__global__ __launch_bounds__(256, 1) void mu_gemm(
    const u16* __restrict__ fiveb, const u16* __restrict__ WKt,
    const u16* __restrict__ WVt, u16* __restrict__ M_all, u16* __restrict__ U_all) {
    __shared__ u16 Cst[256 * 64];
    const int f0 = blockIdx.x * 64, n = blockIdx.y, which = blockIdx.z;
    const u16* vec = fiveb + ((which ? 4 : 1) * HH + n) * TT * DHH;
    const u16* W = (which ? WVt : WKt) + (size_t)n * 262144;
    u16* out = (which ? U_all : M_all) + (size_t)n * 1048576;
    const int tid = threadIdx.x, w = tid >> 6, lane = tid & 63;
    const int quad = lane >> 4, l15 = lane & 15;

    bf16x8 bf[4][2];
#pragma unroll
    for (int nt = 0; nt < 4; ++nt) {
        bf[nt][0] = *(const bf16x8*)&W[(size_t)(f0 + nt * 16 + l15) * 64 + quad * 8];
        bf[nt][1] = *(const bf16x8*)&W[(size_t)(f0 + nt * 16 + l15) * 64 + 32 + quad * 8];
    }
    f32x4 acc[4][4];
#pragma unroll
    for (int mt = 0; mt < 4; ++mt) {
        int trow = w * 64 + mt * 16 + l15;
        bf16x8 a0 = *(const bf16x8*)&vec[trow * 64 + quad * 8];
        bf16x8 a1 = *(const bf16x8*)&vec[trow * 64 + 32 + quad * 8];
#pragma unroll
        for (int nt = 0; nt < 4; ++nt) {
            f32x4 c = {0.f, 0.f, 0.f, 0.f};
            c = MFMA(a0, bf[nt][0], c, 0, 0, 0);
            c = MFMA(a1, bf[nt][1], c, 0, 0, 0);
            acc[mt][nt] = c;
        }
    }
#pragma unroll
    for (int mt = 0; mt < 4; ++mt)
#pragma unroll
        for (int nt = 0; nt < 4; ++nt)
#pragma unroll
            for (int r = 0; r < 4; ++r)
                Cst[(w * 64 + mt * 16 + quad * 4 + r) * 64 + nt * 16 + l15] = f2bf(acc[mt][nt][r]);
    __syncthreads();
    const uint4* src = (const uint4*)&Cst[tid * 64];
    uint4* dst = (uint4*)(out + (size_t)tid * 4096 + f0);
#pragma unroll
    for (int i = 0; i < 8; ++i) dst[i] = src[i];
}

// ---------------- K4: fused trilinear attention — full 64x64 tiles per wave, own t per wave
// grid 1088: n = b&7, j = b>>3 in [0,136): qt0 j<8 (cnt2), qt1 j<24 (cnt2), qt2 j<72, qt3 j<136 (cnt1)
__global__ __launch_bounds__(256, 2) void main_kernel(
    const u16* __restrict__ fiveb, const u16* __restrict__ v1T,
    const u16* __restrict__ M_all, const u16* __restrict__ U_all,
    u16* __restrict__ Zpart, float* __restrict__ Lpart) {
    __shared__ u16 Sb_all[4 * 4608];   // 4 wave-private 64x72 strips
    __shared__ float Lred[256];
    const int tid = threadIdx.x;
    const int b = blockIdx.x, n = b & 7, j = b >> 3;
    const int w = tid >> 6, lane = tid & 63, quad = lane >> 4, l15 = lane & 15;
    int qt, tbase, cnt;
    if (j < 8)       { qt = 0; cnt = 2; tbase = j * 8 + w * 2; }
    else if (j < 24) { qt = 1; cnt = 2; tbase = (j - 8) * 8 + w * 2; }
    else if (j < 72) { qt = 2; cnt = 1; tbase = (j - 24) * 4 + w; }
    else             { qt = 3; cnt = 1; tbase = (j - 72) * 4 + w; }
    const int q0 = qt * 64, nP = qt + 1;

    const u16* k1g = fiveb + (0 * 8 + n) * 16384;
    const u16* qg  = fiveb + (2 * 8 + n) * 16384;
    const u16* v1g = v1T + n * 16384;
    const u16* Mg = M_all + (size_t)(n * 256) * 4096;
    const u16* Ug = U_all + (size_t)(n * 256) * 4096;
    u16* Sb = Sb_all + w * 4608;

    f32x4 Zacc[4][4];
#pragma unroll
    for (int m = 0; m < 4; ++m)
#pragma unroll
        for (int nt = 0; nt < 4; ++nt) Zacc[m][nt] = (f32x4){0.f, 0.f, 0.f, 0.f};
    float lsum[4] = {0.f, 0.f, 0.f, 0.f};

    for (int tt = 0; tt < cnt; ++tt) {
        const int t = tbase + tt;
        const u16* Mt = Mg + (size_t)t * 4096;
        const u16* Ut = Ug + (size_t)t * 4096;

        // ---- QM = q . M_t^T : 32 MFMAs, pack into Sb
        {
            bf16x8 mb[4][2];
#pragma unroll
            for (int nt = 0; nt < 4; ++nt) {
                mb[nt][0] = *(const bf16x8*)&Mt[(nt * 16 + l15) * 64 + quad * 8];
                mb[nt][1] = *(const bf16x8*)&Mt[(nt * 16 + l15) * 64 + 32 + quad * 8];
            }
#pragma unroll
            for (int m = 0; m < 4; ++m) {
                bf16x8 a0 = *(const bf16x8*)&qg[(q0 + m * 16 + l15) * 64 + quad * 8];
                bf16x8 a1 = *(const bf16x8*)&qg[(q0 + m * 16 + l15) * 64 + 32 + quad * 8];
#pragma unroll
                for (int nt = 0; nt < 4; ++nt) {
                    f32x4 c = {0.f, 0.f, 0.f, 0.f};
                    c = MFMA(a0, mb[nt][0], c, 0, 0, 0);
                    c = MFMA(a1, mb[nt][1], c, 0, 0, 0);
#pragma unroll
                    for (int r = 0; r < 4; ++r)
                        Sb[(m * 16 + quad * 4 + r) * 72 + nt * 16 + l15] = f2bf(c[r]);
                }
            }
        }
        // qma A-fragments held in registers through the pt loop
        bf16x8 qma[4][2];
#pragma unroll
        for (int m = 0; m < 4; ++m) {
            qma[m][0] = *(const bf16x8*)&Sb[(m * 16 + l15) * 72 + quad * 8];
            qma[m][1] = *(const bf16x8*)&Sb[(m * 16 + l15) * 72 + 32 + quad * 8];
        }

        f32x4 G[4][4];
#pragma unroll
        for (int m = 0; m < 4; ++m)
#pragma unroll
            for (int nt = 0; nt < 4; ++nt) G[m][nt] = (f32x4){0.f, 0.f, 0.f, 0.f};

        for (int pt = 0; pt < nP; ++pt) {
            // ---- S = QM . k1^T ; mask+exp -> Sb (32 MFMAs)
#pragma unroll
            for (int nt = 0; nt < 4; ++nt) {
                bf16x8 b0 = *(const bf16x8*)&k1g[(pt * 64 + nt * 16 + l15) * 64 + quad * 8];
                bf16x8 b1 = *(const bf16x8*)&k1g[(pt * 64 + nt * 16 + l15) * 64 + 32 + quad * 8];
                const int p = pt * 64 + nt * 16 + l15;
#pragma unroll
                for (int m = 0; m < 4; ++m) {
                    f32x4 s = {0.f, 0.f, 0.f, 0.f};
                    s = MFMA(qma[m][0], b0, s, 0, 0, 0);
                    s = MFMA(qma[m][1], b1, s, 0, 0, 0);
#pragma unroll
                    for (int r = 0; r < 4; ++r) {
                        const int q = q0 + m * 16 + quad * 4 + r;
                        float wv = (p <= q && t <= q) ? __expf(s[r] * 0.015625f) : 0.f;
                        Sb[(m * 16 + quad * 4 + r) * 72 + nt * 16 + l15] = f2bf(wv);
                    }
                }
            }
            // ---- G += P . v1 (32 MFMAs); lsum from P A-fragments
            bf16x8 vb[4][2];
#pragma unroll
            for (int nt = 0; nt < 4; ++nt) {
                vb[nt][0] = *(const bf16x8*)&v1g[(nt * 16 + l15) * 256 + pt * 64 + quad * 8];
                vb[nt][1] = *(const bf16x8*)&v1g[(nt * 16 + l15) * 256 + pt * 64 + 32 + quad * 8];
            }
#pragma unroll
            for (int m = 0; m < 4; ++m) {
                bf16x8 pa0 = *(const bf16x8*)&Sb[(m * 16 + l15) * 72 + quad * 8];
                bf16x8 pa1 = *(const bf16x8*)&Sb[(m * 16 + l15) * 72 + 32 + quad * 8];
                lsum[m] += sum8v(pa0) + sum8v(pa1);
#pragma unroll
                for (int nt = 0; nt < 4; ++nt) {
                    G[m][nt] = MFMA(pa0, vb[nt][0], G[m][nt], 0, 0, 0);
                    G[m][nt] = MFMA(pa1, vb[nt][1], G[m][nt], 0, 0, 0);
                }
            }
        }
        // ---- Z += G . U_t (32 MFMAs, G via Sb roundtrip)
#pragma unroll
        for (int m = 0; m < 4; ++m)
#pragma unroll
            for (int nt = 0; nt < 4; ++nt)
#pragma unroll
                for (int r = 0; r < 4; ++r)
                    Sb[(m * 16 + quad * 4 + r) * 72 + nt * 16 + l15] = f2bf(G[m][nt][r]);
        bf16x8 ub[4][2];
#pragma unroll
        for (int nt = 0; nt < 4; ++nt) {
            ub[nt][0] = *(const bf16x8*)&Ut[(nt * 16 + l15) * 64 + quad * 8];
            ub[nt][1] = *(const bf16x8*)&Ut[(nt * 16 + l15) * 64 + 32 + quad * 8];
        }
#pragma unroll
        for (int m = 0; m < 4; ++m) {
            bf16x8 ga0 = *(const bf16x8*)&Sb[(m * 16 + l15) * 72 + quad * 8];
            bf16x8 ga1 = *(const bf16x8*)&Sb[(m * 16 + l15) * 72 + 32 + quad * 8];
#pragma unroll
            for (int nt = 0; nt < 4; ++nt) {
                Zacc[m][nt] = MFMA(ga0, ub[nt][0], Zacc[m][nt], 0, 0, 0);
                Zacc[m][nt] = MFMA(ga1, ub[nt][1], Zacc[m][nt], 0, 0, 0);
            }
        }
    }

    // ---- reductions: pack Zacc into own strip; L row-sums
#pragma unroll
    for (int m = 0; m < 4; ++m)
#pragma unroll
        for (int nt = 0; nt < 4; ++nt)
#pragma unroll
            for (int r = 0; r < 4; ++r)
                Sb[(m * 16 + quad * 4 + r) * 72 + nt * 16 + l15] = f2bf(Zacc[m][nt][r]);
#pragma unroll
    for (int m = 0; m < 4; ++m) {
        lsum[m] += __shfl_xor(lsum[m], 16);
        lsum[m] += __shfl_xor(lsum[m], 32);
    }
    if (quad == 0) {
#pragma unroll
        for (int m = 0; m < 4; ++m) Lred[w * 64 + m * 16 + l15] = lsum[m];
    }
    __syncthreads();
    {   // cross-wave Z sum: thread -> (row, 16 cols)
        const int row = tid >> 2, c0 = (tid & 3) * 16;
        float acc[16];
#pragma unroll
        for (int i = 0; i < 16; ++i) acc[i] = 0.f;
#pragma unroll
        for (int ww = 0; ww < 4; ++ww) {
            const u16* s = Sb_all + ww * 4608 + row * 72 + c0;
            uint4 v0 = *(const uint4*)s, v1 = *(const uint4*)(s + 8);
            float f[16];
            unpack2(v0.x, f[0], f[1]); unpack2(v0.y, f[2], f[3]);
            unpack2(v0.z, f[4], f[5]); unpack2(v0.w, f[6], f[7]);
            unpack2(v1.x, f[8], f[9]); unpack2(v1.y, f[10], f[11]);
            unpack2(v1.z, f[12], f[13]); unpack2(v1.w, f[14], f[15]);
#pragma unroll
            for (int i = 0; i < 16; ++i) acc[i] += f[i];
        }
        __attribute__((aligned(16))) u16 tmp[16];
#pragma unroll
        for (int i = 0; i < 16; ++i) tmp[i] = f2bf(acc[i]);
        u16* d = Zpart + (size_t)b * 4096 + row * 64 + c0;
        *(uint4*)d = *(uint4*)tmp;
        *(uint4*)(d + 8) = *(uint4*)(tmp + 8);
    }
    if (tid < 64)
        Lpart[b * 64 + tid] = Lred[tid] + Lred[64 + tid] + Lred[128 + tid] + Lred[192 + tid];
}

// ---------------- K5: zn[t][h*64+e] = bf16( sum_j Zpart / sum_j Lpart )
__global__ __launch_bounds__(256) void zn_kernel(
    const u16* __restrict__ Zpart, const float* __restrict__ Lpart, u16* __restrict__ zn) {
    const int flat = (blockIdx.x * 256 + threadIdx.x) * 4;
    const int t = flat >> 9, he = flat & 511, h = he >> 6, e = he & 63;
    const int qt = t >> 6, qq = t & 63;
    int jb, je;
    if (qt == 0)      { jb = 0;  je = 8;   }
    else if (qt == 1) { jb = 8;  je = 24;  }
    else if (qt == 2) { jb = 24; je = 72;  }
    else              { jb = 72; je = 136; }
    float4 sz = {0.f, 0.f, 0.f, 0.f};
    float sl = 0.f;
    for (int j = jb; j < je; ++j) {
        const int bb = j * 8 + h;
        uint2 zv = *(const uint2*)(Zpart + (size_t)bb * 4096 + qq * 64 + e);
        float f0, f1, f2, f3;
        unpack2(zv.x, f0, f1); unpack2(zv.y, f2, f3);
        sz.x += f0; sz.y += f1; sz.z += f2; sz.w += f3;
        sl += Lpart[bb * 64 + qq];
    }
    const float inv = 1.f / sl;
    __attribute__((aligned(8))) u16 t4[4];
    t4[0] = f2bf(sz.x * inv); t4[1] = f2bf(sz.y * inv);
    t4[2] = f2bf(sz.z * inv); t4[3] = f2bf(sz.w * inv);
    *(uint2*)(zn + flat) = *(uint2*)t4;
}

// ---------------- K6: out = zn @ Wot^T + b_out (fp32 out), MFMA
__global__ __launch_bounds__(256) void out_mfma(
    const u16* __restrict__ zn, const u16* __restrict__ Wot,
    const float* __restrict__ b_out, float* __restrict__ out) {
    const int tid = threadIdx.x, w = tid >> 6, lane = tid & 63;
    const int quad = lane >> 4, l15 = lane & 15;
    const int m0 = blockIdx.x * 64 + w * 16;
    const int c0 = blockIdx.y * 64;
    f32x4 acc[4];
#pragma unroll
    for (int nt = 0; nt < 4; ++nt) acc[nt] = (f32x4){0.f, 0.f, 0.f, 0.f};
    for (int kc = 0; kc < 16; ++kc) {
        bf16x8 a = *(const bf16x8*)&zn[(size_t)(m0 + l15) * 512 + kc * 32 + quad * 8];
#pragma unroll
        for (int nt = 0; nt < 4; ++nt) {
            bf16x8 b = *(const bf16x8*)&Wot[(size_t)(c0 + nt * 16 + l15) * 512 + kc * 32 + quad * 8];
            acc[nt] = MFMA(a, b, acc[nt], 0, 0, 0);
        }
    }
#pragma unroll
    for (int nt = 0; nt < 4; ++nt) {
        const int col = c0 + nt * 16 + l15;
        const float b = b_out[col];
#pragma unroll
        for (int r = 0; r < 4; ++r)
            out[(size_t)(m0 + quad * 4 + r) * 512 + col] = acc[nt][r] + b;
    }
}

extern "C" void kernel_launch(void* const* d_in, const int* in_sizes, int n_in,
                              void* d_out, int out_size, void* d_ws, size_t ws_size,
                              hipStream_t stream) {
    const float* x       = (const float*)d_in[0];
    const float* W_kkqvv = (const float*)d_in[1];
    const float* b_kkqvv = (const float*)d_in[2];
    const float* W_Kq    = (const float*)d_in[3];
    const float* W_Vq    = (const float*)d_in[4];
    const float* W_out   = (const float*)d_in[5];
    const float* b_out   = (const float*)d_in[6];

    char* base = (char*)d_ws;
    u16*   fiveb = (u16*)base;                      // 1,310,720 B
    u16*   WKt   = (u16*)(base + 1843200);          // 4 MB
    u16*   WVt   = (u16*)(base + 6037504);          // 4 MB
    u16*   M_all = (u16*)(base + 10231808);         // 16 MB
    u16*   U_all = (u16*)(base + 27009024);         // 16 MB
    // aliases:
    u16*   Zpart = (u16*)(base + 1310720);          // 1088 x 8 KB bf16 over gap+WKt+WVt (dead after mu_gemm)
    u16*   Wt    = (u16*)(base + 10231808);         // dead after proj (over M_all)
    u16*   xb    = (u16*)(base + 12853248);
    u16*   Wot   = (u16*)(base + 43786240);         // 524,288 B
    u16*   v1T   = (u16*)(base + 44310528);         // 262,144 B
    u16*   zn    = (u16*)(base + 44572672);         // 262,144 B
    float* Lpart = (float*)(base + 44834816);       // 278,528 B (end ~45.1 MB)

    prep_kernel<<<392, 256, 0, stream>>>(W_kkqvv, W_out, x, Wt, Wot, xb);
    proj_mfma<<<dim3(4, 40), 256, 0, stream>>>(xb, Wt, b_kkqvv, fiveb, v1T);
    transpose_w<<<dim3(64, 8, 2), 256, 0, stream>>>(W_Kq, W_Vq, WKt, WVt);
    mu_gemm<<<dim3(64, 8, 2), 256, 0, stream>>>(fiveb, WKt, WVt, M_all, U_all);
    main_kernel<<<1088, 256, 0, stream>>>(fiveb, v1T, M_all, U_all, Zpart, Lpart);
    zn_kernel<<<128, 256, 0, stream>>>(Zpart, Lpart, zn);
    out_mfma<<<dim3(4, 8), 256, 0, stream>>>(zn, Wot, b_out, (float*)d_out);
}

// Round 11
// 233.475 us; speedup vs baseline: 1.4373x; 1.0075x over previous
//
#include <hip/hip_runtime.h>

typedef unsigned short u16;
typedef unsigned int u32;
typedef __attribute__((ext_vector_type(8))) short bf16x8;
typedef __attribute__((ext_vector_type(4))) float f32x4;
#define MFMA __builtin_amdgcn_mfma_f32_16x16x32_bf16

#define TT 256
#define DD 512
#define HH 8
#define DHH 64
#define NC 2560   // 5*H*DH

__device__ __forceinline__ u16 f2bf(float f) {
    u32 x; __builtin_memcpy(&x, &f, 4);
    u32 r = (x + 0x7FFFu + ((x >> 16) & 1u)) >> 16;
    return (u16)r;
}
__device__ __forceinline__ void unpack2(u32 u, float& lo, float& hi) {
    u32 l = u << 16, h = u & 0xFFFF0000u;
    __builtin_memcpy(&lo, &l, 4); __builtin_memcpy(&hi, &h, 4);
}
__device__ __forceinline__ float sum8v(bf16x8 v) {
    uint4 u; __builtin_memcpy(&u, &v, 16);
    float f[8];
    unpack2(u.x, f[0], f[1]); unpack2(u.y, f[2], f[3]);
    unpack2(u.z, f[4], f[5]); unpack2(u.w, f[6], f[7]);
    return ((f[0]+f[1])+(f[2]+f[3]))+((f[4]+f[5])+(f[6]+f[7]));
}

// ---------------- K0: prep — Wt = bf16(W_kkqvv)^T, Wot = bf16(W_out)^T, xb = bf16(x)
__global__ __launch_bounds__(256) void prep_kernel(
    const float* __restrict__ W1, const float* __restrict__ Wo,
    const float* __restrict__ x,
    u16* __restrict__ Wt, u16* __restrict__ Wot, u16* __restrict__ xb) {
    __shared__ float S[64 * 65];
    const int bid = blockIdx.x, tid = threadIdx.x;
    if (bid < 384) {
        int tc, tr, Cw;
        const float* src; u16* dst;
        if (bid < 320) { tc = bid % 40; tr = bid / 40; src = W1; dst = Wt;  Cw = 2560; }
        else { int b2 = bid - 320; tc = b2 % 8; tr = b2 / 8; src = Wo; dst = Wot; Cw = 512; }
        {
            int X = tid >> 2, c0 = (tid & 3) * 16;
            const float4* s4 = (const float4*)(src + (size_t)(tr * 64 + X) * Cw + tc * 64 + c0);
            float4 v0 = s4[0], v1 = s4[1], v2 = s4[2], v3 = s4[3];
            float* d = &S[X * 65 + c0];
            d[0]=v0.x; d[1]=v0.y; d[2]=v0.z; d[3]=v0.w;
            d[4]=v1.x; d[5]=v1.y; d[6]=v1.z; d[7]=v1.w;
            d[8]=v2.x; d[9]=v2.y; d[10]=v2.z; d[11]=v2.w;
            d[12]=v3.x; d[13]=v3.y; d[14]=v3.z; d[15]=v3.w;
        }
        __syncthreads();
        {
            int Y = tid >> 2, x0 = (tid & 3) * 16;
            __attribute__((aligned(16))) u16 tmp[16];
#pragma unroll
            for (int xx = 0; xx < 16; ++xx) tmp[xx] = f2bf(S[(x0 + xx) * 65 + Y]);
            u16* o = dst + (size_t)(tc * 64 + Y) * 512 + tr * 64 + x0;
            *(uint4*)o = *(uint4*)tmp;
            *(uint4*)(o + 8) = *(uint4*)(tmp + 8);
        }
    } else {
        int b3 = bid - 384;            // 8 blocks cast x -> xb
        size_t base = (size_t)(b3 * 256 + tid) * 64;
        const float4* s = (const float4*)(x + base);
#pragma unroll
        for (int i = 0; i < 8; ++i) {
            float4 lo = s[2 * i], hi = s[2 * i + 1];
            __attribute__((aligned(16))) u16 t8[8];
            t8[0]=f2bf(lo.x); t8[1]=f2bf(lo.y); t8[2]=f2bf(lo.z); t8[3]=f2bf(lo.w);
            t8[4]=f2bf(hi.x); t8[5]=f2bf(hi.y); t8[6]=f2bf(hi.z); t8[7]=f2bf(hi.w);
            ((uint4*)(xb + base))[i] = *(uint4*)t8;
        }
    }
}

// ---------------- K1: proj MFMA: proj = xb @ Wt^T + b -> fiveb (v=3 -> v1T transposed)
__global__ __launch_bounds__(256) void proj_mfma(
    const u16* __restrict__ xb, const u16* __restrict__ Wt,
    const float* __restrict__ bias, u16* __restrict__ fiveb, u16* __restrict__ v1T) {
    const int tid = threadIdx.x, w = tid >> 6, lane = tid & 63;
    const int quad = lane >> 4, l15 = lane & 15;
    const int m0 = blockIdx.x * 64 + w * 16;
    const int c0 = blockIdx.y * 64;
    f32x4 acc[4];
#pragma unroll
    for (int nt = 0; nt < 4; ++nt) acc[nt] = (f32x4){0.f, 0.f, 0.f, 0.f};
    for (int kc = 0; kc < 16; ++kc) {
        bf16x8 a = *(const bf16x8*)&xb[(size_t)(m0 + l15) * 512 + kc * 32 + quad * 8];
#pragma unroll
        for (int nt = 0; nt < 4; ++nt) {
            bf16x8 b = *(const bf16x8*)&Wt[(size_t)(c0 + nt * 16 + l15) * 512 + kc * 32 + quad * 8];
            acc[nt] = MFMA(a, b, acc[nt], 0, 0, 0);
        }
    }
#pragma unroll
    for (int nt = 0; nt < 4; ++nt) {
        const int col = c0 + nt * 16 + l15;
        const float b = bias[col];
        const int v = col >> 9, h = (col >> 6) & 7, e = col & 63;
#pragma unroll
        for (int r = 0; r < 4; ++r) {
            const int t = m0 + quad * 4 + r;
            u16 val = f2bf(acc[nt][r] + b);
            if (v == 3) v1T[(h * 64 + e) * 256 + t] = val;
            else        fiveb[((v * 8 + h) * 256 + t) * 64 + e] = val;
        }
    }
}

// ---------------- K2: transpose weights to K-contiguous bf16
__global__ __launch_bounds__(256) void transpose_w(
    const float* __restrict__ WK, const float* __restrict__ WV,
    u16* __restrict__ WKt, u16* __restrict__ WVt) {
    __shared__ float S[64 * 65];
    const int outer = blockIdx.x, n = blockIdx.y, which = blockIdx.z;
    const float* in = (which ? WV : WK) + ((size_t)(n * 64 + outer)) * 4096;
    u16* outbase = (which ? WVt : WKt) + (size_t)n * 262144;
    const int tid = threadIdx.x;
    {
        int X = tid >> 2, c0 = (tid & 3) * 16;
        const float4* s = (const float4*)(in + X * 64 + c0);
        float4 v0 = s[0], v1 = s[1], v2 = s[2], v3 = s[3];
        float* d = &S[X * 65 + c0];
        d[0]=v0.x; d[1]=v0.y; d[2]=v0.z; d[3]=v0.w;
        d[4]=v1.x; d[5]=v1.y; d[6]=v1.z; d[7]=v1.w;
        d[8]=v2.x; d[9]=v2.y; d[10]=v2.z; d[11]=v2.w;
        d[12]=v3.x; d[13]=v3.y; d[14]=v3.z; d[15]=v3.w;
    }
    __syncthreads();
    {
        int Y = tid >> 2, x0 = (tid & 3) * 16;
        __attribute__((aligned(16))) u16 tmp[16];
#pragma unroll
        for (int xx = 0; xx < 16; ++xx) tmp[xx] = f2bf(S[(x0 + xx) * 65 + Y]);
        size_t strideY = which ? 4096 : 64;
        size_t strideO = which ? 64 : 4096;
        u16* d = outbase + (size_t)Y * strideY + (size_t)outer * strideO + x0;
        *(uint4*)d = *(uint4*)tmp;
        *(uint4*)(d + 8) = *(uint4*)(tmp + 8);
    }
}

// ---------------- K3: M_all[n][t][f] = sum_j k2[t,j]*WKt[n][f][j]  (U analog)
__global__ __launch_bounds__(256, 1) void mu_gemm(
    const u16* __restrict__ fiveb, const u16* __restrict__ WKt,
    const u16* __restrict__ WVt, u16* __restrict__ M_all, u16* __restrict__ U_all) {
    __shared__ u16 Cst[256 * 64];
    const int f0 = blockIdx.x * 64, n = blockIdx.y, which = blockIdx.z;
    const u16* vec = fiveb + ((which ? 4 : 1) * HH + n) * TT * DHH;
    const u16* W = (which ? WVt : WKt) + (size_t)n * 262144;
    u16* out = (which ? U_all : M_all) + (size_t)n * 1048576;
    const int tid = threadIdx.x, w = tid >> 6, lane = tid & 63;
    const int quad = lane >> 4, l15 = lane & 15;

    bf16x8 bf[4][2];
#pragma unroll
    for (int nt = 0; nt < 4; ++nt) {
        bf[nt][0] = *(const bf16x8*)&W[(size_t)(f0 + nt * 16 + l15) * 64 + quad * 8];
        bf[nt][1] = *(const bf16x8*)&W[(size_t)(f0 + nt * 16 + l15) * 64 + 32 + quad * 8];
    }
    f32x4 acc[4][4];
#pragma unroll
    for (int mt = 0; mt < 4; ++mt) {
        int trow = w * 64 + mt * 16 + l15;
        bf16x8 a0 = *(const bf16x8*)&vec[trow * 64 + quad * 8];
        bf16x8 a1 = *(const bf16x8*)&vec[trow * 64 + 32 + quad * 8];
#pragma unroll
        for (int nt = 0; nt < 4; ++nt) {
            f32x4 c = {0.f, 0.f, 0.f, 0.f};
            c = MFMA(a0, bf[nt][0], c, 0, 0, 0);
            c = MFMA(a1, bf[nt][1], c, 0, 0, 0);
            acc[mt][nt] = c;
        }
    }
#pragma unroll
    for (int mt = 0; mt < 4; ++mt)
#pragma unroll
        for (int nt = 0; nt < 4; ++nt)
#pragma unroll
            for (int r = 0; r < 4; ++r)
                Cst[(w * 64 + mt * 16 + quad * 4 + r) * 64 + nt * 16 + l15] = f2bf(acc[mt][nt][r]);
    __syncthreads();
    const uint4* src = (const uint4*)&Cst[tid * 64];
    uint4* dst = (uint4*)(out + (size_t)tid * 4096 + f0);
#pragma unroll
    for (int i = 0; i < 8; ++i) dst[i] = src[i];
}

// ---------------- K4: fused trilinear attention — wave-pair per 64-row q-tile (m=2, no spills)
// grid 928: n = b&7, j = b>>3 in [0,116):
//   qt0 j<4: cnt=8; qt1 j<20: cnt=4; qt2 j<52: cnt=3; qt3 j<116: cnt=2. Block covers 2*cnt t's.
__global__ __launch_bounds__(256, 2) void main_kernel(
    const u16* __restrict__ fiveb, const u16* __restrict__ v1T,
    const u16* __restrict__ M_all, const u16* __restrict__ U_all,
    u16* __restrict__ Zpart, float* __restrict__ Lpart) {
    __shared__ u16 Sb_all[4 * 2304];   // 4 wave-private 32x72 strips
    __shared__ float Lred[128];
    const int tid = threadIdx.x;
    const int b = blockIdx.x, n = b & 7, j = b >> 3;
    const int w = tid >> 6, lane = tid & 63, quad = lane >> 4, l15 = lane & 15;
    const int half = w & 1, par = w >> 1;
    int qt, t0, cnt;
    if (j < 4)       { qt = 0; cnt = 8; t0 = j * 16; }
    else if (j < 20) { qt = 1; cnt = 4; t0 = (j - 4) * 8; }
    else if (j < 52) { qt = 2; cnt = 3; t0 = (j - 20) * 6; }
    else             { qt = 3; cnt = 2; t0 = (j - 52) * 4; }
    const int q0 = qt * 64, nP = qt + 1;
    const int qbase = q0 + half * 32;

    const u16* k1g = fiveb + (0 * 8 + n) * 16384;
    const u16* qg  = fiveb + (2 * 8 + n) * 16384;
    const u16* v1g = v1T + n * 16384;
    const u16* Mg = M_all + (size_t)(n * 256) * 4096;
    const u16* Ug = U_all + (size_t)(n * 256) * 4096;
    u16* Sb = Sb_all + w * 2304;

    // q A-fragments: 2 m-tiles, loop-invariant
    bf16x8 qa[2][2];
#pragma unroll
    for (int m = 0; m < 2; ++m) {
        qa[m][0] = *(const bf16x8*)&qg[(qbase + m * 16 + l15) * 64 + quad * 8];
        qa[m][1] = *(const bf16x8*)&qg[(qbase + m * 16 + l15) * 64 + 32 + quad * 8];
    }

    f32x4 Zacc[2][4];
#pragma unroll
    for (int m = 0; m < 2; ++m)
#pragma unroll
        for (int nt = 0; nt < 4; ++nt) Zacc[m][nt] = (f32x4){0.f, 0.f, 0.f, 0.f};
    float lsum[2] = {0.f, 0.f};

    for (int c = 0; c < cnt; ++c) {
        const int t = t0 + c * 2 + par;
        const u16* Mt = Mg + (size_t)t * 4096;
        const u16* Ut = Ug + (size_t)t * 4096;

        // ---- QM = q . M_t^T (16 MFMAs) -> Sb
        {
            bf16x8 mb[4][2];
#pragma unroll
            for (int nt = 0; nt < 4; ++nt) {
                mb[nt][0] = *(const bf16x8*)&Mt[(nt * 16 + l15) * 64 + quad * 8];
                mb[nt][1] = *(const bf16x8*)&Mt[(nt * 16 + l15) * 64 + 32 + quad * 8];
            }
#pragma unroll
            for (int m = 0; m < 2; ++m)
#pragma unroll
                for (int nt = 0; nt < 4; ++nt) {
                    f32x4 cc = {0.f, 0.f, 0.f, 0.f};
                    cc = MFMA(qa[m][0], mb[nt][0], cc, 0, 0, 0);
                    cc = MFMA(qa[m][1], mb[nt][1], cc, 0, 0, 0);
#pragma unroll
                    for (int r = 0; r < 4; ++r)
                        Sb[(m * 16 + quad * 4 + r) * 72 + nt * 16 + l15] = f2bf(cc[r]);
                }
        }
        bf16x8 qma[2][2];
#pragma unroll
        for (int m = 0; m < 2; ++m) {
            qma[m][0] = *(const bf16x8*)&Sb[(m * 16 + l15) * 72 + quad * 8];
            qma[m][1] = *(const bf16x8*)&Sb[(m * 16 + l15) * 72 + 32 + quad * 8];
        }

        f32x4 G[2][4];
#pragma unroll
        for (int m = 0; m < 2; ++m)
#pragma unroll
            for (int nt = 0; nt < 4; ++nt) G[m][nt] = (f32x4){0.f, 0.f, 0.f, 0.f};

        for (int pt = 0; pt < nP; ++pt) {
            // ---- S = QM . k1^T ; mask+exp -> Sb (16 MFMAs)
#pragma unroll
            for (int nt = 0; nt < 4; ++nt) {
                bf16x8 b0 = *(const bf16x8*)&k1g[(pt * 64 + nt * 16 + l15) * 64 + quad * 8];
                bf16x8 b1 = *(const bf16x8*)&k1g[(pt * 64 + nt * 16 + l15) * 64 + 32 + quad * 8];
                const int p = pt * 64 + nt * 16 + l15;
#pragma unroll
                for (int m = 0; m < 2; ++m) {
                    f32x4 s = {0.f, 0.f, 0.f, 0.f};
                    s = MFMA(qma[m][0], b0, s, 0, 0, 0);
                    s = MFMA(qma[m][1], b1, s, 0, 0, 0);
#pragma unroll
                    for (int r = 0; r < 4; ++r) {
                        const int q = qbase + m * 16 + quad * 4 + r;
                        float wv = (p <= q && t <= q) ? __expf(s[r] * 0.015625f) : 0.f;
                        Sb[(m * 16 + quad * 4 + r) * 72 + nt * 16 + l15] = f2bf(wv);
                    }
                }
            }
            // ---- G += P . v1 (16 MFMAs); lsum from P A-fragments
            bf16x8 vb[4][2];
#pragma unroll
            for (int nt = 0; nt < 4; ++nt) {
                vb[nt][0] = *(const bf16x8*)&v1g[(nt * 16 + l15) * 256 + pt * 64 + quad * 8];
                vb[nt][1] = *(const bf16x8*)&v1g[(nt * 16 + l15) * 256 + pt * 64 + 32 + quad * 8];
            }
#pragma unroll
            for (int m = 0; m < 2; ++m) {
                bf16x8 pa0 = *(const bf16x8*)&Sb[(m * 16 + l15) * 72 + quad * 8];
                bf16x8 pa1 = *(const bf16x8*)&Sb[(m * 16 + l15) * 72 + 32 + quad * 8];
                lsum[m] += sum8v(pa0) + sum8v(pa1);
#pragma unroll
                for (int nt = 0; nt < 4; ++nt) {
                    G[m][nt] = MFMA(pa0, vb[nt][0], G[m][nt], 0, 0, 0);
                    G[m][nt] = MFMA(pa1, vb[nt][1], G[m][nt], 0, 0, 0);
                }
            }
        }
        // ---- Z += G . U_t (16 MFMAs, G via Sb roundtrip)
#pragma unroll
        for (int m = 0; m < 2; ++m)
#pragma unroll
            for (int nt = 0; nt < 4; ++nt)
#pragma unroll
                for (int r = 0; r < 4; ++r)
                    Sb[(m * 16 + quad * 4 + r) * 72 + nt * 16 + l15] = f2bf(G[m][nt][r]);
        bf16x8 ub[4][2];
#pragma unroll
        for (int nt = 0; nt < 4; ++nt) {
            ub[nt][0] = *(const bf16x8*)&Ut[(nt * 16 + l15) * 64 + quad * 8];
            ub[nt][1] = *(const bf16x8*)&Ut[(nt * 16 + l15) * 64 + 32 + quad * 8];
        }
#pragma unroll
        for (int m = 0; m < 2; ++m) {
            bf16x8 ga0 = *(const bf16x8*)&Sb[(m * 16 + l15) * 72 + quad * 8];
            bf16x8 ga1 = *(const bf16x8*)&Sb[(m * 16 + l15) * 72 + 32 + quad * 8];
#pragma unroll
            for (int nt = 0; nt < 4; ++nt) {
                Zacc[m][nt] = MFMA(ga0, ub[nt][0], Zacc[m][nt], 0, 0, 0);
                Zacc[m][nt] = MFMA(ga1, ub[nt][1], Zacc[m][nt], 0, 0, 0);
            }
        }
    }

    // ---- pack Zacc into own strip; L row-sums
#pragma unroll
    for (int m = 0; m < 2; ++m)
#pragma unroll
        for (int nt = 0; nt < 4; ++nt)
#pragma unroll
            for (int r = 0; r < 4; ++r)
                Sb[(m * 16 + quad * 4 + r) * 72 + nt * 16 + l15] = f2bf(Zacc[m][nt][r]);
#pragma unroll
    for (int m = 0; m < 2; ++m) {
        lsum[m] += __shfl_xor(lsum[m], 16);
        lsum[m] += __shfl_xor(lsum[m], 32);
    }
    if (quad == 0) {
#pragma unroll
        for (int m = 0; m < 2; ++m) Lred[w * 32 + m * 16 + l15] = lsum[m];
    }
    __syncthreads();
    {   // cross-parity Z sum: row r from strips (r>>5) and (r>>5)+2
        const int row = tid >> 2, cc = (tid & 3) * 16;
        const int hs = row >> 5, lr = row & 31;
        const u16* s0 = Sb_all + hs * 2304 + lr * 72 + cc;
        const u16* s1 = Sb_all + (hs + 2) * 2304 + lr * 72 + cc;
        uint4 a0 = *(const uint4*)s0, a1 = *(const uint4*)(s0 + 8);
        uint4 b0 = *(const uint4*)s1, b1 = *(const uint4*)(s1 + 8);
        float fa[16], fb[16];
        unpack2(a0.x, fa[0], fa[1]); unpack2(a0.y, fa[2], fa[3]);
        unpack2(a0.z, fa[4], fa[5]); unpack2(a0.w, fa[6], fa[7]);
        unpack2(a1.x, fa[8], fa[9]); unpack2(a1.y, fa[10], fa[11]);
        unpack2(a1.z, fa[12], fa[13]); unpack2(a1.w, fa[14], fa[15]);
        unpack2(b0.x, fb[0], fb[1]); unpack2(b0.y, fb[2], fb[3]);
        unpack2(b0.z, fb[4], fb[5]); unpack2(b0.w, fb[6], fb[7]);
        unpack2(b1.x, fb[8], fb[9]); unpack2(b1.y, fb[10], fb[11]);
        unpack2(b1.z, fb[12], fb[13]); unpack2(b1.w, fb[14], fb[15]);
        __attribute__((aligned(16))) u16 tmp[16];
#pragma unroll
        for (int i = 0; i < 16; ++i) tmp[i] = f2bf(fa[i] + fb[i]);
        u16* d = Zpart + (size_t)b * 4096 + row * 64 + cc;
        *(uint4*)d = *(uint4*)tmp;
        *(uint4*)(d + 8) = *(uint4*)(tmp + 8);
    }
    if (tid < 64) {
        const int hs = tid >> 5, lr = tid & 31;
        Lpart[b * 64 + tid] = Lred[hs * 32 + lr] + Lred[(hs + 2) * 32 + lr];
    }
}

// ---------------- K5: zn[t][h*64+e] = bf16( sum_j Zpart / sum_j Lpart )
__global__ __launch_bounds__(256) void zn_kernel(
    const u16* __restrict__ Zpart, const float* __restrict__ Lpart, u16* __restrict__ zn) {
    const int flat = (blockIdx.x * 256 + threadIdx.x) * 4;
    const int t = flat >> 9, he = flat & 511, h = he >> 6, e = he & 63;
    const int qt = t >> 6, qq = t & 63;
    int jb, je;
    if (qt == 0)      { jb = 0;  je = 4;   }
    else if (qt == 1) { jb = 4;  je = 20;  }
    else if (qt == 2) { jb = 20; je = 52;  }
    else              { jb = 52; je = 116; }
    float4 sz = {0.f, 0.f, 0.f, 0.f};
    float sl = 0.f;
    for (int j = jb; j < je; ++j) {
        const int bb = j * 8 + h;
        uint2 zv = *(const uint2*)(Zpart + (size_t)bb * 4096 + qq * 64 + e);
        float f0, f1, f2, f3;
        unpack2(zv.x, f0, f1); unpack2(zv.y, f2, f3);
        sz.x += f0; sz.y += f1; sz.z += f2; sz.w += f3;
        sl += Lpart[bb * 64 + qq];
    }
    const float inv = 1.f / sl;
    __attribute__((aligned(8))) u16 t4[4];
    t4[0] = f2bf(sz.x * inv); t4[1] = f2bf(sz.y * inv);
    t4[2] = f2bf(sz.z * inv); t4[3] = f2bf(sz.w * inv);
    *(uint2*)(zn + flat) = *(uint2*)t4;
}

// ---------------- K6: out = zn @ Wot^T + b_out (fp32 out), MFMA
__global__ __launch_bounds__(256) void out_mfma(
    const u16* __restrict__ zn, const u16* __restrict__ Wot,
    const float* __restrict__ b_out, float* __restrict__ out) {
    const int tid = threadIdx.x, w = tid >> 6, lane = tid & 63;
    const int quad = lane >> 4, l15 = lane & 15;
    const int m0 = blockIdx.x * 64 + w * 16;
    const int c0 = blockIdx.y * 64;
    f32x4 acc[4];
#pragma unroll
    for (int nt = 0; nt < 4; ++nt) acc[nt] = (f32x4){0.f, 0.f, 0.f, 0.f};
    for (int kc = 0; kc < 16; ++kc) {
        bf16x8 a = *(const bf16x8*)&zn[(size_t)(m0 + l15) * 512 + kc * 32 + quad * 8];
#pragma unroll
        for (int nt = 0; nt < 4; ++nt) {
            bf16x8 b = *(const bf16x8*)&Wot[(size_t)(c0 + nt * 16 + l15) * 512 + kc * 32 + quad * 8];
            acc[nt] = MFMA(a, b, acc[nt], 0, 0, 0);
        }
    }
#pragma unroll
    for (int nt = 0; nt < 4; ++nt) {
        const int col = c0 + nt * 16 + l15;
        const float b = b_out[col];
#pragma unroll
        for (int r = 0; r < 4; ++r)
            out[(size_t)(m0 + quad * 4 + r) * 512 + col] = acc[nt][r] + b;
    }
}

extern "C" void kernel_launch(void* const* d_in, const int* in_sizes, int n_in,
                              void* d_out, int out_size, void* d_ws, size_t ws_size,
                              hipStream_t stream) {
    const float* x       = (const float*)d_in[0];
    const float* W_kkqvv = (const float*)d_in[1];
    const float* b_kkqvv = (const float*)d_in[2];
    const float* W_Kq    = (const float*)d_in[3];
    const float* W_Vq    = (const float*)d_in[4];
    const float* W_out   = (const float*)d_in[5];
    const float* b_out   = (const float*)d_in[6];

    char* base = (char*)d_ws;
    u16*   fiveb = (u16*)base;                      // 1,310,720 B
    u16*   WKt   = (u16*)(base + 1843200);          // 4 MB
    u16*   WVt   = (u16*)(base + 6037504);          // 4 MB
    u16*   M_all = (u16*)(base + 10231808);         // 16 MB
    u16*   U_all = (u16*)(base + 27009024);         // 16 MB
    // aliases:
    u16*   Zpart = (u16*)(base + 1310720);          // 928 x 8 KB bf16 over gap+WKt+WVt (dead after mu_gemm)
    u16*   Wt    = (u16*)(base + 10231808);         // dead after proj (over M_all)
    u16*   xb    = (u16*)(base + 12853248);
    u16*   Wot   = (u16*)(base + 43786240);         // 524,288 B
    u16*   v1T   = (u16*)(base + 44310528);         // 262,144 B
    u16*   zn    = (u16*)(base + 44572672);         // 262,144 B
    float* Lpart = (float*)(base + 44834816);       // 237,568 B (end ~45.1 MB)

    prep_kernel<<<392, 256, 0, stream>>>(W_kkqvv, W_out, x, Wt, Wot, xb);
    proj_mfma<<<dim3(4, 40), 256, 0, stream>>>(xb, Wt, b_kkqvv, fiveb, v1T);
    transpose_w<<<dim3(64, 8, 2), 256, 0, stream>>>(W_Kq, W_Vq, WKt, WVt);
    mu_gemm<<<dim3(64, 8, 2), 256, 0, stream>>>(fiveb, WKt, WVt, M_all, U_all);
    main_kernel<<<928, 256, 0, stream>>>(fiveb, v1T, M_all, U_all, Zpart, Lpart);
    zn_kernel<<<128, 256, 0, stream>>>(Zpart, Lpart, zn);
    out_mfma<<<dim3(4, 8), 256, 0, stream>>>(zn, Wot, b_out, (float*)d_out);
}

// Round 12
// 198.147 us; speedup vs baseline: 1.6936x; 1.1783x over previous
//
#include <hip/hip_runtime.h>

typedef unsigned short u16;
typedef unsigned int u32;
typedef __attribute__((ext_vector_type(8))) short bf16x8;
typedef __attribute__((ext_vector_type(4))) float f32x4;
#define MFMA __builtin_amdgcn_mfma_f32_16x16x32_bf16

#define TT 256
#define DD 512
#define HH 8
#define DHH 64
#define NC 2560   // 5*H*DH

__device__ __forceinline__ u16 f2bf(float f) {
    u32 x; __builtin_memcpy(&x, &f, 4);
    u32 r = (x + 0x7FFFu + ((x >> 16) & 1u)) >> 16;
    return (u16)r;
}
__device__ __forceinline__ void unpack2(u32 u, float& lo, float& hi) {
    u32 l = u << 16, h = u & 0xFFFF0000u;
    __builtin_memcpy(&lo, &l, 4); __builtin_memcpy(&hi, &h, 4);
}

// ---------------- K0: prep — Wt = bf16(W_kkqvv)^T, Wot = bf16(W_out)^T, xb = bf16(x)
__global__ __launch_bounds__(256) void prep_kernel(
    const float* __restrict__ W1, const float* __restrict__ Wo,
    const float* __restrict__ x,
    u16* __restrict__ Wt, u16* __restrict__ Wot, u16* __restrict__ xb) {
    __shared__ float S[64 * 65];
    const int bid = blockIdx.x, tid = threadIdx.x;
    if (bid < 384) {
        int tc, tr, Cw;
        const float* src; u16* dst;
        if (bid < 320) { tc = bid % 40; tr = bid / 40; src = W1; dst = Wt;  Cw = 2560; }
        else { int b2 = bid - 320; tc = b2 % 8; tr = b2 / 8; src = Wo; dst = Wot; Cw = 512; }
        {
            int X = tid >> 2, c0 = (tid & 3) * 16;
            const float4* s4 = (const float4*)(src + (size_t)(tr * 64 + X) * Cw + tc * 64 + c0);
            float4 v0 = s4[0], v1 = s4[1], v2 = s4[2], v3 = s4[3];
            float* d = &S[X * 65 + c0];
            d[0]=v0.x; d[1]=v0.y; d[2]=v0.z; d[3]=v0.w;
            d[4]=v1.x; d[5]=v1.y; d[6]=v1.z; d[7]=v1.w;
            d[8]=v2.x; d[9]=v2.y; d[10]=v2.z; d[11]=v2.w;
            d[12]=v3.x; d[13]=v3.y; d[14]=v3.z; d[15]=v3.w;
        }
        __syncthreads();
        {
            int Y = tid >> 2, x0 = (tid & 3) * 16;
            __attribute__((aligned(16))) u16 tmp[16];
#pragma unroll
            for (int xx = 0; xx < 16; ++xx) tmp[xx] = f2bf(S[(x0 + xx) * 65 + Y]);
            u16* o = dst + (size_t)(tc * 64 + Y) * 512 + tr * 64 + x0;
            *(uint4*)o = *(uint4*)tmp;
            *(uint4*)(o + 8) = *(uint4*)(tmp + 8);
        }
    } else {
        int b3 = bid - 384;            // 8 blocks cast x -> xb
        size_t base = (size_t)(b3 * 256 + tid) * 64;
        const float4* s = (const float4*)(x + base);
#pragma unroll
        for (int i = 0; i < 8; ++i) {
            float4 lo = s[2 * i], hi = s[2 * i + 1];
            __attribute__((aligned(16))) u16 t8[8];
            t8[0]=f2bf(lo.x); t8[1]=f2bf(lo.y); t8[2]=f2bf(lo.z); t8[3]=f2bf(lo.w);
            t8[4]=f2bf(hi.x); t8[5]=f2bf(hi.y); t8[6]=f2bf(hi.z); t8[7]=f2bf(hi.w);
            ((uint4*)(xb + base))[i] = *(uint4*)t8;
        }
    }
}

// ---------------- K1: proj MFMA: proj = xb @ Wt^T + b -> fiveb (v=3 -> v1T transposed)
__global__ __launch_bounds__(256) void proj_mfma(
    const u16* __restrict__ xb, const u16* __restrict__ Wt,
    const float* __restrict__ bias, u16* __restrict__ fiveb, u16* __restrict__ v1T) {
    const int tid = threadIdx.x, w = tid >> 6, lane = tid & 63;
    const int quad = lane >> 4, l15 = lane & 15;
    const int m0 = blockIdx.x * 64 + w * 16;
    const int c0 = blockIdx.y * 64;
    f32x4 acc[4];
#pragma unroll
    for (int nt = 0; nt < 4; ++nt) acc[nt] = (f32x4){0.f, 0.f, 0.f, 0.f};
    for (int kc = 0; kc < 16; ++kc) {
        bf16x8 a = *(const bf16x8*)&xb[(size_t)(m0 + l15) * 512 + kc * 32 + quad * 8];
#pragma unroll
        for (int nt = 0; nt < 4; ++nt) {
            bf16x8 b = *(const bf16x8*)&Wt[(size_t)(c0 + nt * 16 + l15) * 512 + kc * 32 + quad * 8];
            acc[nt] = MFMA(a, b, acc[nt], 0, 0, 0);
        }
    }
#pragma unroll
    for (int nt = 0; nt < 4; ++nt) {
        const int col = c0 + nt * 16 + l15;
        const float b = bias[col];
        const int v = col >> 9, h = (col >> 6) & 7, e = col & 63;
#pragma unroll
        for (int r = 0; r < 4; ++r) {
            const int t = m0 + quad * 4 + r;
            u16 val = f2bf(acc[nt][r] + b);
            if (v == 3) v1T[(h * 64 + e) * 256 + t] = val;
            else        fiveb[((v * 8 + h) * 256 + t) * 64 + e] = val;
        }
    }
}

// ---------------- K2: transpose weights to K-contiguous bf16
__global__ __launch_bounds__(256) void transpose_w(
    const float* __restrict__ WK, const float* __restrict__ WV,
    u16* __restrict__ WKt, u16* __restrict__ WVt) {
    __shared__ float S[64 * 65];
    const int outer = blockIdx.x, n = blockIdx.y, which = blockIdx.z;
    const float* in = (which ? WV : WK) + ((size_t)(n * 64 + outer)) * 4096;
    u16* outbase = (which ? WVt : WKt) + (size_t)n * 262144;
    const int tid = threadIdx.x;
    {
        int X = tid >> 2, c0 = (tid & 3) * 16;
        const float4* s = (const float4*)(in + X * 64 + c0);
        float4 v0 = s[0], v1 = s[1], v2 = s[2], v3 = s[3];
        float* d = &S[X * 65 + c0];
        d[0]=v0.x; d[1]=v0.y; d[2]=v0.z; d[3]=v0.w;
        d[4]=v1.x; d[5]=v1.y; d[6]=v1.z; d[7]=v1.w;
        d[8]=v2.x; d[9]=v2.y; d[10]=v2.z; d[11]=v2.w;
        d[12]=v3.x; d[13]=v3.y; d[14]=v3.z; d[15]=v3.w;
    }
    __syncthreads();
    {
        int Y = tid >> 2, x0 = (tid & 3) * 16;
        __attribute__((aligned(16))) u16 tmp[16];
#pragma unroll
        for (int xx = 0; xx < 16; ++xx) tmp[xx] = f2bf(S[(x0 + xx) * 65 + Y]);
        size_t strideY = which ? 4096 : 64;
        size_t strideO = which ? 64 : 4096;
        u16* d = outbase + (size_t)Y * strideY + (size_t)outer * strideO + x0;
        *(uint4*)d = *(uint4*)tmp;
        *(uint4*)(d + 8) = *(uint4*)(tmp + 8);
    }
}

// ---------------- K3: M_all[n][t][f] = sum_j k2[t,j]*WKt[n][f][j]  (U analog)
__global__ __launch_bounds__(256, 1) void mu_gemm(
    const u16* __restrict__ fiveb, const u16* __restrict__ WKt,
    const u16* __restrict__ WVt, u16* __restrict__ M_all, u16* __restrict__ U_all) {
    __shared__ u16 Cst[256 * 64];
    const int f0 = blockIdx.x * 64, n = blockIdx.y, which = blockIdx.z;
    const u16* vec = fiveb + ((which ? 4 : 1) * HH + n) * TT * DHH;
    const u16* W = (which ? WVt : WKt) + (size_t)n * 262144;
    u16* out = (which ? U_all : M_all) + (size_t)n * 1048576;
    const int tid = threadIdx.x, w = tid >> 6, lane = tid & 63;
    const int quad = lane >> 4, l15 = lane & 15;

    bf16x8 bf[4][2];
#pragma unroll
    for (int nt = 0; nt < 4; ++nt) {
        bf[nt][0] = *(const bf16x8*)&W[(size_t)(f0 + nt * 16 + l15) * 64 + quad * 8];
        bf[nt][1] = *(const bf16x8*)&W[(size_t)(f0 + nt * 16 + l15) * 64 + 32 + quad * 8];
    }
    f32x4 acc[4][4];
#pragma unroll
    for (int mt = 0; mt < 4; ++mt) {
        int trow = w * 64 + mt * 16 + l15;
        bf16x8 a0 = *(const bf16x8*)&vec[trow * 64 + quad * 8];
        bf16x8 a1 = *(const bf16x8*)&vec[trow * 64 + 32 + quad * 8];
#pragma unroll
        for (int nt = 0; nt < 4; ++nt) {
            f32x4 c = {0.f, 0.f, 0.f, 0.f};
            c = MFMA(a0, bf[nt][0], c, 0, 0, 0);
            c = MFMA(a1, bf[nt][1], c, 0, 0, 0);
            acc[mt][nt] = c;
        }
    }
#pragma unroll
    for (int mt = 0; mt < 4; ++mt)
#pragma unroll
        for (int nt = 0; nt < 4; ++nt)
#pragma unroll
            for (int r = 0; r < 4; ++r)
                Cst[(w * 64 + mt * 16 + quad * 4 + r) * 64 + nt * 16 + l15] = f2bf(acc[mt][nt][r]);
    __syncthreads();
    const uint4* src = (const uint4*)&Cst[tid * 64];
    uint4* dst = (uint4*)(out + (size_t)tid * 4096 + f0);
#pragma unroll
    for (int i = 0; i < 8; ++i) dst[i] = src[i];
}

// ---------------- K4: fused trilinear attention — m=1: wave owns 16 q-rows, 4 waves share t
// grid 896: n = b&7, j = b>>3 in [0,112): qt0 j<16 cnt4; qt1 j<48 cnt2; qt2 j<80 cnt2; qt3 j<112 cnt2
__global__ __launch_bounds__(256, 4) void main_kernel(
    const u16* __restrict__ fiveb, const u16* __restrict__ v1T,
    const u16* __restrict__ M_all, const u16* __restrict__ U_all,
    u16* __restrict__ Zpart, float* __restrict__ Lpart) {
    __shared__ u16 Sb_all[4 * 1152];   // 4 wave-private 16x72 strips
    const int tid = threadIdx.x;
    const int b = blockIdx.x, n = b & 7, j = b >> 3;
    const int w = tid >> 6, lane = tid & 63, quad = lane >> 4, l15 = lane & 15;
    int qt, t0, cnt;
    if (j < 16)      { qt = 0; cnt = 4; t0 = j * 4; }
    else if (j < 48) { qt = 1; cnt = 2; t0 = (j - 16) * 2; }
    else if (j < 80) { qt = 2; cnt = 2; t0 = (j - 48) * 2; }
    else             { qt = 3; cnt = 2; t0 = (j - 80) * 2; }
    const int nP = qt + 1;
    const int qrow0 = qt * 64 + w * 16;     // this wave's 16 q rows

    const u16* k1g = fiveb + (0 * 8 + n) * 16384;
    const u16* qg  = fiveb + (2 * 8 + n) * 16384;
    const u16* v1g = v1T + n * 16384;
    const u16* Mg = M_all + (size_t)(n * 256) * 4096;
    const u16* Ug = U_all + (size_t)(n * 256) * 4096;
    u16* Sb = Sb_all + w * 1152;

    // q A-fragment (rows qrow0..qrow0+15), loop-invariant
    const bf16x8 qa0 = *(const bf16x8*)&qg[(qrow0 + l15) * 64 + quad * 8];
    const bf16x8 qa1 = *(const bf16x8*)&qg[(qrow0 + l15) * 64 + 32 + quad * 8];

    // all-ones bf16 B-fragment for row-sum MFMA
    bf16x8 ones;
    { uint4 ou = {0x3F803F80u, 0x3F803F80u, 0x3F803F80u, 0x3F803F80u};
      __builtin_memcpy(&ones, &ou, 16); }

    f32x4 Zacc[4];
#pragma unroll
    for (int nt = 0; nt < 4; ++nt) Zacc[nt] = (f32x4){0.f, 0.f, 0.f, 0.f};
    f32x4 Lacc = {0.f, 0.f, 0.f, 0.f};

    for (int c = 0; c < cnt; ++c) {
        const int t = t0 + c;
        const u16* Mt = Mg + (size_t)t * 4096;
        const u16* Ut = Ug + (size_t)t * 4096;

        // ---- QM = q . M_t^T (8 MFMAs) -> Sb strip
#pragma unroll
        for (int nt = 0; nt < 4; ++nt) {
            bf16x8 b0 = *(const bf16x8*)&Mt[(nt * 16 + l15) * 64 + quad * 8];
            bf16x8 b1 = *(const bf16x8*)&Mt[(nt * 16 + l15) * 64 + 32 + quad * 8];
            f32x4 cc = {0.f, 0.f, 0.f, 0.f};
            cc = MFMA(qa0, b0, cc, 0, 0, 0);
            cc = MFMA(qa1, b1, cc, 0, 0, 0);
#pragma unroll
            for (int r = 0; r < 4; ++r)
                Sb[(quad * 4 + r) * 72 + nt * 16 + l15] = f2bf(cc[r]);
        }
        const bf16x8 qma0 = *(const bf16x8*)&Sb[l15 * 72 + quad * 8];
        const bf16x8 qma1 = *(const bf16x8*)&Sb[l15 * 72 + 32 + quad * 8];

        f32x4 G[4];
#pragma unroll
        for (int nt = 0; nt < 4; ++nt) G[nt] = (f32x4){0.f, 0.f, 0.f, 0.f};

        for (int pt = 0; pt < nP; ++pt) {
            // ---- S = QM . k1^T ; mask+exp -> Sb (8 MFMAs)
#pragma unroll
            for (int nt = 0; nt < 4; ++nt) {
                bf16x8 b0 = *(const bf16x8*)&k1g[(pt * 64 + nt * 16 + l15) * 64 + quad * 8];
                bf16x8 b1 = *(const bf16x8*)&k1g[(pt * 64 + nt * 16 + l15) * 64 + 32 + quad * 8];
                f32x4 s = {0.f, 0.f, 0.f, 0.f};
                s = MFMA(qma0, b0, s, 0, 0, 0);
                s = MFMA(qma1, b1, s, 0, 0, 0);
                const int p = pt * 64 + nt * 16 + l15;
#pragma unroll
                for (int r = 0; r < 4; ++r) {
                    const int q = qrow0 + quad * 4 + r;
                    float wv = (p <= q && t <= q) ? __expf(s[r] * 0.015625f) : 0.f;
                    Sb[(quad * 4 + r) * 72 + nt * 16 + l15] = f2bf(wv);
                }
            }
            bf16x8 pa0 = *(const bf16x8*)&Sb[l15 * 72 + quad * 8];
            bf16x8 pa1 = *(const bf16x8*)&Sb[l15 * 72 + 32 + quad * 8];
            // L row-sums via ones-MFMA (replaces sum8v + shfl)
            Lacc = MFMA(pa0, ones, Lacc, 0, 0, 0);
            Lacc = MFMA(pa1, ones, Lacc, 0, 0, 0);
            // ---- G += P . v1 (8 MFMAs)
#pragma unroll
            for (int nt = 0; nt < 4; ++nt) {
                bf16x8 b0 = *(const bf16x8*)&v1g[(nt * 16 + l15) * 256 + pt * 64 + quad * 8];
                bf16x8 b1 = *(const bf16x8*)&v1g[(nt * 16 + l15) * 256 + pt * 64 + 32 + quad * 8];
                G[nt] = MFMA(pa0, b0, G[nt], 0, 0, 0);
                G[nt] = MFMA(pa1, b1, G[nt], 0, 0, 0);
            }
        }
        // ---- Z += G . U_t (8 MFMAs, G via Sb roundtrip)
#pragma unroll
        for (int nt = 0; nt < 4; ++nt)
#pragma unroll
            for (int r = 0; r < 4; ++r)
                Sb[(quad * 4 + r) * 72 + nt * 16 + l15] = f2bf(G[nt][r]);
        bf16x8 ga0 = *(const bf16x8*)&Sb[l15 * 72 + quad * 8];
        bf16x8 ga1 = *(const bf16x8*)&Sb[l15 * 72 + 32 + quad * 8];
#pragma unroll
        for (int nt = 0; nt < 4; ++nt) {
            bf16x8 b0 = *(const bf16x8*)&Ut[(nt * 16 + l15) * 64 + quad * 8];
            bf16x8 b1 = *(const bf16x8*)&Ut[(nt * 16 + l15) * 64 + 32 + quad * 8];
            Zacc[nt] = MFMA(ga0, b0, Zacc[nt], 0, 0, 0);
            Zacc[nt] = MFMA(ga1, b1, Zacc[nt], 0, 0, 0);
        }
    }

    // ---- epilogue: pack Zacc -> Sb, vector store; Lacc direct float4 store
#pragma unroll
    for (int nt = 0; nt < 4; ++nt)
#pragma unroll
        for (int r = 0; r < 4; ++r)
            Sb[(quad * 4 + r) * 72 + nt * 16 + l15] = f2bf(Zacc[nt][r]);
    {
        const int row = lane >> 2, cc = (lane & 3) * 16;
        uint4 z0 = *(const uint4*)&Sb[row * 72 + cc];
        uint4 z1 = *(const uint4*)&Sb[row * 72 + cc + 8];
        uint4* d = (uint4*)(Zpart + (size_t)b * 4096 + (w * 16 + row) * 64 + cc);
        d[0] = z0; d[1] = z1;
    }
    if (l15 == 0) {
        float4 lv;
        lv.x = Lacc[0]; lv.y = Lacc[1]; lv.z = Lacc[2]; lv.w = Lacc[3];
        *(float4*)(Lpart + b * 64 + w * 16 + quad * 4) = lv;
    }
}

// ---------------- K5: zn[t][h*64+e] = bf16( sum_j Zpart / sum_j Lpart )
__global__ __launch_bounds__(256) void zn_kernel(
    const u16* __restrict__ Zpart, const float* __restrict__ Lpart, u16* __restrict__ zn) {
    const int flat = (blockIdx.x * 256 + threadIdx.x) * 4;
    const int t = flat >> 9, he = flat & 511, h = he >> 6, e = he & 63;
    const int qt = t >> 6, qq = t & 63;
    int jb, je;
    if (qt == 0)      { jb = 0;  je = 16;  }
    else if (qt == 1) { jb = 16; je = 48;  }
    else if (qt == 2) { jb = 48; je = 80;  }
    else              { jb = 80; je = 112; }
    float4 sz = {0.f, 0.f, 0.f, 0.f};
    float sl = 0.f;
    for (int j = jb; j < je; ++j) {
        const int bb = j * 8 + h;
        uint2 zv = *(const uint2*)(Zpart + (size_t)bb * 4096 + qq * 64 + e);
        float f0, f1, f2, f3;
        unpack2(zv.x, f0, f1); unpack2(zv.y, f2, f3);
        sz.x += f0; sz.y += f1; sz.z += f2; sz.w += f3;
        sl += Lpart[bb * 64 + qq];
    }
    const float inv = 1.f / sl;
    __attribute__((aligned(8))) u16 t4[4];
    t4[0] = f2bf(sz.x * inv); t4[1] = f2bf(sz.y * inv);
    t4[2] = f2bf(sz.z * inv); t4[3] = f2bf(sz.w * inv);
    *(uint2*)(zn + flat) = *(uint2*)t4;
}

// ---------------- K6: out = zn @ Wot^T + b_out (fp32 out), MFMA
__global__ __launch_bounds__(256) void out_mfma(
    const u16* __restrict__ zn, const u16* __restrict__ Wot,
    const float* __restrict__ b_out, float* __restrict__ out) {
    const int tid = threadIdx.x, w = tid >> 6, lane = tid & 63;
    const int quad = lane >> 4, l15 = lane & 15;
    const int m0 = blockIdx.x * 64 + w * 16;
    const int c0 = blockIdx.y * 64;
    f32x4 acc[4];
#pragma unroll
    for (int nt = 0; nt < 4; ++nt) acc[nt] = (f32x4){0.f, 0.f, 0.f, 0.f};
    for (int kc = 0; kc < 16; ++kc) {
        bf16x8 a = *(const bf16x8*)&zn[(size_t)(m0 + l15) * 512 + kc * 32 + quad * 8];
#pragma unroll
        for (int nt = 0; nt < 4; ++nt) {
            bf16x8 b = *(const bf16x8*)&Wot[(size_t)(c0 + nt * 16 + l15) * 512 + kc * 32 + quad * 8];
            acc[nt] = MFMA(a, b, acc[nt], 0, 0, 0);
        }
    }
#pragma unroll
    for (int nt = 0; nt < 4; ++nt) {
        const int col = c0 + nt * 16 + l15;
        const float b = b_out[col];
#pragma unroll
        for (int r = 0; r < 4; ++r)
            out[(size_t)(m0 + quad * 4 + r) * 512 + col] = acc[nt][r] + b;
    }
}

extern "C" void kernel_launch(void* const* d_in, const int* in_sizes, int n_in,
                              void* d_out, int out_size, void* d_ws, size_t ws_size,
                              hipStream_t stream) {
    const float* x       = (const float*)d_in[0];
    const float* W_kkqvv = (const float*)d_in[1];
    const float* b_kkqvv = (const float*)d_in[2];
    const float* W_Kq    = (const float*)d_in[3];
    const float* W_Vq    = (const float*)d_in[4];
    const float* W_out   = (const float*)d_in[5];
    const float* b_out   = (const float*)d_in[6];

    char* base = (char*)d_ws;
    u16*   fiveb = (u16*)base;                      // 1,310,720 B
    u16*   WKt   = (u16*)(base + 1843200);          // 4 MB
    u16*   WVt   = (u16*)(base + 6037504);          // 4 MB
    u16*   M_all = (u16*)(base + 10231808);         // 16 MB
    u16*   U_all = (u16*)(base + 27009024);         // 16 MB
    // aliases:
    u16*   Zpart = (u16*)(base + 1310720);          // 896 x 8 KB bf16 over gap+WKt+WVt (dead after mu_gemm)
    u16*   Wt    = (u16*)(base + 10231808);         // dead after proj (over M_all)
    u16*   xb    = (u16*)(base + 12853248);
    u16*   Wot   = (u16*)(base + 43786240);         // 524,288 B
    u16*   v1T   = (u16*)(base + 44310528);         // 262,144 B
    u16*   zn    = (u16*)(base + 44572672);         // 262,144 B
    float* Lpart = (float*)(base + 44834816);       // 229,376 B (end ~45.1 MB)

    prep_kernel<<<392, 256, 0, stream>>>(W_kkqvv, W_out, x, Wt, Wot, xb);
    proj_mfma<<<dim3(4, 40), 256, 0, stream>>>(xb, Wt, b_kkqvv, fiveb, v1T);
    transpose_w<<<dim3(64, 8, 2), 256, 0, stream>>>(W_Kq, W_Vq, WKt, WVt);
    mu_gemm<<<dim3(64, 8, 2), 256, 0, stream>>>(fiveb, WKt, WVt, M_all, U_all);
    main_kernel<<<896, 256, 0, stream>>>(fiveb, v1T, M_all, U_all, Zpart, Lpart);
    zn_kernel<<<128, 256, 0, stream>>>(Zpart, Lpart, zn);
    out_mfma<<<dim3(4, 8), 256, 0, stream>>>(zn, Wot, b_out, (float*)d_out);
}